// Round 5
// baseline (309.435 us; speedup 1.0000x reference)
//
#include <hip/hip_runtime.h>
#include <math.h>

// ---------- types ----------
typedef __attribute__((ext_vector_type(8))) __bf16 bf16x8;
typedef __attribute__((ext_vector_type(4))) float  f32x4;
typedef unsigned short ushort_t;
typedef unsigned int   uint_t;

static __device__ inline f32x4 mfma16(bf16x8 a, bf16x8 b, f32x4 c) {
    return __builtin_amdgcn_mfma_f32_16x16x32_bf16(a, b, c, 0, 0, 0);
}

static __device__ inline ushort_t f2b(float f) {
    uint_t u = __builtin_bit_cast(uint_t, f);
    u = (u + 0x7FFFu + ((u >> 16) & 1u)) >> 16;
    return (ushort_t)u;
}
static __device__ inline float b2f(ushort_t u) {
    uint_t x = ((uint_t)u) << 16;
    return __builtin_bit_cast(float, x);
}
static __device__ inline bf16x8 ld8(const ushort_t* p) {
    uint4 v = *(const uint4*)p;
    return __builtin_bit_cast(bf16x8, v);
}
static __device__ inline float fexp2(float x) {
#if __has_builtin(__builtin_amdgcn_exp2f)
    return __builtin_amdgcn_exp2f(x);
#else
    return exp2f(x);
#endif
}

// async global->LDS, 16B per lane; LDS dst = base + lane*16 (wave-uniform base!)
static __device__ inline void gl_lds16(const ushort_t* g, ushort_t* l) {
    __builtin_amdgcn_global_load_lds(
        (const __attribute__((address_space(1))) void*)(g),
        (__attribute__((address_space(3))) void*)(l),
        16, 0, 0);
}

// ---------- ws layout (peak = 62,914,560 B, R1 layout) ----------
#define WS_XB     0          //  8 MiB x bf16           [2048,2048]   (dead after QKV gemm)
#define WS_WQKV   8388608    // 12 MiB [Wq;Wk;Wv] bf16  [3072,2048]   (dead after QKV gemm)
#define WS_WO     20971520   //  8 MiB Wo bf16          [2048,2048]
#define WS_P0     29360128   // 12 MiB QKV partial 0 bf16 [2048,3072] (dead after fuse)
#define WS_P1     41943040   // 12 MiB QKV partial 1 bf16 [2048,3072] (dead after fuse)
#define WS_QBB    0          //  8 MiB q roped bf16     (overlays xb)
#define WS_KBB    8388608    //  2 MiB k roped bf16     (overlays wqkvb head)
#define WS_VTG    10485760   //  2 MiB V^T bf16 [512,2048]
#define WS_AB     12582912   //  8 MiB attn out bf16    (ends exactly at WS_WO)
#define WS_O0     29360128   // 16 MiB O partial 0 fp32 (overlays p0)
#define WS_O1     46137344   // 16 MiB O partial 1 fp32 (ends 62914560)

// ---------- fp32 -> bf16 convert for x|Wq|Wk|Wv|Wo (contiguous dst) ----------
__global__ __launch_bounds__(256) void cvt_all(const float* __restrict__ x,
                                               const float* __restrict__ wq,
                                               const float* __restrict__ wk,
                                               const float* __restrict__ wv,
                                               const float* __restrict__ wo,
                                               ushort_t* __restrict__ dst) {
    const size_t i = (size_t)(blockIdx.x * 256 + threadIdx.x) * 4;
    const float* src; size_t off;
    if (i < 4194304)       { src = x;  off = 0; }
    else if (i < 8388608)  { src = wq; off = 4194304; }
    else if (i < 9437184)  { src = wk; off = 8388608; }
    else if (i < 10485760) { src = wv; off = 9437184; }
    else                   { src = wo; off = 10485760; }
    float4 v = *(const float4*)(src + (i - off));
    ushort4 o;
    o.x = f2b(v.x); o.y = f2b(v.y); o.z = f2b(v.z); o.w = f2b(v.w);
    *(ushort4*)(dst + i) = o;
}

// ---------- GEMM-NT tile body: 128(M)x64(N), BK=64, R1 sync skeleton ----------
// R10: occupancy over amortization. 24 KB LDS (As 16K + Bs 8K) -> 6 blocks/CU
// LDS cap; grid supplies 6/CU (QKV) / 4/CU (O-proj) vs 3/2 at 128x128.
// Waves 2x2: wave tile 64(M)x32(N), acc[4][2]. 16 MFMA/wave per K-step.
template <int OUTB>
static __device__ void gemm_tile(const ushort_t* __restrict__ A,
                                 const ushort_t* __restrict__ Bt,
                                 void* __restrict__ Cout,
                                 int N, int K, long m0, long n0,
                                 int kbeg, int kend,
                                 ushort_t* As, ushort_t* Bs) {
    const int tid  = threadIdx.x;
    const int lane = tid & 63, wave = tid >> 6;
    const int wr = wave >> 1, wc = wave & 1;
    const int qn = lane & 15, quad = lane >> 4;

    const ushort_t* ga = A  + (m0 + lane) * K + wave * 8;
    const ushort_t* gb = Bt + (n0 + lane) * K + wave * 8;
    ushort_t* laL = As + wave * 1024;          // A: 8 chunks of [row128][8]
    ushort_t* laH = As + (wave + 4) * 1024;
    ushort_t* lbL = Bs + wave * 512;           // B: 8 chunks of [col64][8]
    ushort_t* lbH = Bs + (wave + 4) * 512;

    f32x4 zero = {0.f, 0.f, 0.f, 0.f};
    f32x4 acc[4][2];
    for (int i = 0; i < 4; i++)
        for (int j = 0; j < 2; j++) acc[i][j] = zero;

    const long r64 = 64L * K;
    for (int k0 = kbeg; k0 < kend; k0 += 64) {
        __syncthreads();
        gl_lds16(ga + k0,            laL);
        gl_lds16(ga + r64 + k0,      laL + 512);
        gl_lds16(ga + k0 + 32,       laH);
        gl_lds16(ga + r64 + k0 + 32, laH + 512);
        gl_lds16(gb + k0,            lbL);
        gl_lds16(gb + k0 + 32,       lbH);
        __syncthreads();
        #pragma unroll
        for (int kk = 0; kk < 2; kk++) {
            bf16x8 af[4], bfr[2];
            const int cbA = (kk * 4 + quad) * 1024;
            const int cbB = (kk * 4 + quad) * 512;
            #pragma unroll
            for (int i = 0; i < 4; i++)
                af[i] = *(const bf16x8*)(As + cbA + (wr * 64 + i * 16 + qn) * 8);
            #pragma unroll
            for (int j = 0; j < 2; j++)
                bfr[j] = *(const bf16x8*)(Bs + cbB + (wc * 32 + j * 16 + qn) * 8);
            #pragma unroll
            for (int i = 0; i < 4; i++)
                #pragma unroll
                for (int j = 0; j < 2; j++)
                    acc[i][j] = mfma16(af[i], bfr[j], acc[i][j]);
        }
    }
    #pragma unroll
    for (int i = 0; i < 4; i++)
        #pragma unroll
        for (int j = 0; j < 2; j++)
            #pragma unroll
            for (int r = 0; r < 4; r++) {
                long row = m0 + wr * 64 + i * 16 + quad * 4 + r;
                long col = n0 + wc * 32 + j * 16 + qn;
                if (OUTB)
                    ((ushort_t*)Cout)[row * N + col] = f2b(acc[i][j][r]);
                else
                    ((float*)Cout)[row * N + col] = acc[i][j][r];
            }
}

// ---------- split-K=2 GEMM wrapper: blockIdx.z picks K-half and dest slab ----------
template <int OUTB>
__global__ __launch_bounds__(256) void gemm_split(const ushort_t* __restrict__ A,
                                                  const ushort_t* __restrict__ Bt,
                                                  void* __restrict__ C0,
                                                  void* __restrict__ C1,
                                                  int N, int K) {
    __shared__ ushort_t As[8192];   // 16 KB
    __shared__ ushort_t Bs[4096];   //  8 KB
    const int half = blockIdx.z;
    const int kh = K >> 1;
    gemm_tile<OUTB>(A, Bt, half ? C1 : C0, N, K,
                    (long)blockIdx.y * 128, (long)blockIdx.x * 64,
                    half * kh, half * kh + kh, As, Bs);
}

// ---------- fused combine + RoPE + V-transpose (R1 verbatim) ----------
__global__ __launch_bounds__(256) void fuse_crv(const ushort_t* __restrict__ p0,
                                                const ushort_t* __restrict__ p1,
                                                const float* __restrict__ cs,
                                                const float* __restrict__ sn,
                                                ushort_t* __restrict__ qd,
                                                ushort_t* __restrict__ kd,
                                                ushort_t* __restrict__ vt) {
    __shared__ ushort_t tl[64][65];
    const int cx = blockIdx.x;               // 0..47
    const int ty = blockIdx.y;               // 0..31
    const int r  = threadIdx.x >> 2;         // 0..63
    const int c0 = (threadIdx.x & 3) << 4;   // 0,16,32,48
    const int t  = ty * 64 + r;
    const size_t base = (size_t)t * 3072 + cx * 64;

    if (cx < 40) {                           // q or k: combine + rope
        const int cp = c0 ^ 32;
        float own[16], par[16];
        #pragma unroll
        for (int jj = 0; jj < 2; jj++) {
            uint4 a = *(const uint4*)(p0 + base + c0 + jj * 8);
            uint4 b = *(const uint4*)(p1 + base + c0 + jj * 8);
            uint4 c = *(const uint4*)(p0 + base + cp + jj * 8);
            uint4 d = *(const uint4*)(p1 + base + cp + jj * 8);
            const ushort_t* pa = (const ushort_t*)&a;
            const ushort_t* pb = (const ushort_t*)&b;
            const ushort_t* pc = (const ushort_t*)&c;
            const ushort_t* pd = (const ushort_t*)&d;
            #pragma unroll
            for (int e = 0; e < 8; e++) {
                own[jj * 8 + e] = b2f(pa[e]) + b2f(pb[e]);
                par[jj * 8 + e] = b2f(pc[e]) + b2f(pd[e]);
            }
        }
        float cs16[16], sn16[16];
        #pragma unroll
        for (int jj = 0; jj < 4; jj++) {
            float4 c4 = *(const float4*)(cs + (size_t)t * 64 + c0 + jj * 4);
            float4 s4 = *(const float4*)(sn + (size_t)t * 64 + c0 + jj * 4);
            cs16[jj * 4 + 0] = c4.x; cs16[jj * 4 + 1] = c4.y;
            cs16[jj * 4 + 2] = c4.z; cs16[jj * 4 + 3] = c4.w;
            sn16[jj * 4 + 0] = s4.x; sn16[jj * 4 + 1] = s4.y;
            sn16[jj * 4 + 2] = s4.z; sn16[jj * 4 + 3] = s4.w;
        }
        const float scale = (cx < 32) ? 0.18033688f : 1.0f;  // q: (1/8)*log2e
        union { ushort_t u[16]; uint4 v[2]; } o;
        #pragma unroll
        for (int j = 0; j < 16; j++) {
            const int d = c0 + j;
            const float pr = (d < 32) ? -par[j] : par[j];
            o.u[j] = f2b((own[j] * cs16[j] + pr * sn16[j]) * scale);
        }
        if (cx < 32) {
            ushort_t* dst = qd + (size_t)t * 2048 + cx * 64 + c0;
            *(uint4*)dst = o.v[0]; *(uint4*)(dst + 8) = o.v[1];
        } else {
            ushort_t* dst = kd + (size_t)t * 512 + (cx - 32) * 64 + c0;
            *(uint4*)dst = o.v[0]; *(uint4*)(dst + 8) = o.v[1];
        }
    } else {                                 // v: combine + transpose via LDS
        #pragma unroll
        for (int jj = 0; jj < 2; jj++) {
            uint4 a = *(const uint4*)(p0 + base + c0 + jj * 8);
            uint4 b = *(const uint4*)(p1 + base + c0 + jj * 8);
            const ushort_t* pa = (const ushort_t*)&a;
            const ushort_t* pb = (const ushort_t*)&b;
            #pragma unroll
            for (int e = 0; e < 8; e++)
                tl[r][c0 + jj * 8 + e] = f2b(b2f(pa[e]) + b2f(pb[e]));
        }
        __syncthreads();
        const int rr  = threadIdx.x >> 3;        // 0..31
        const int cc8 = (threadIdx.x & 7) * 8;
        const int db = (cx - 40) * 64, tb = ty * 64;
        #pragma unroll
        for (int h = 0; h < 2; h++) {
            const int d = rr + h * 32;
            ushort4 o0, o1;
            o0.x = tl[cc8 + 0][d]; o0.y = tl[cc8 + 1][d];
            o0.z = tl[cc8 + 2][d]; o0.w = tl[cc8 + 3][d];
            o1.x = tl[cc8 + 4][d]; o1.y = tl[cc8 + 5][d];
            o1.z = tl[cc8 + 6][d]; o1.w = tl[cc8 + 7][d];
            *(ushort4*)(vt + (size_t)(db + d) * 2048 + tb + cc8)     = o0;
            *(ushort4*)(vt + (size_t)(db + d) * 2048 + tb + cc8 + 4) = o1;
        }
    }
}

// ---------- combine O partials -> fp32 out ----------
__global__ __launch_bounds__(256) void combine_o(const float4* __restrict__ s0,
                                                 const float4* __restrict__ s1,
                                                 float4* __restrict__ out) {
    for (int i = blockIdx.x * 256 + threadIdx.x; i < 1048576; i += 2048 * 256) {
        float4 a = s0[i], b = s1[i];
        float4 r; r.x = a.x + b.x; r.y = a.y + b.y; r.z = a.z + b.z; r.w = a.w + b.w;
        out[i] = r;
    }
}

// ---------- flash attention, causal, GQA G=4 (R2 version: 64 q-rows + setprio) ----------
__global__ __launch_bounds__(256) void attn_kernel(const ushort_t* __restrict__ Q,
                                                   const ushort_t* __restrict__ Kb,
                                                   const ushort_t* __restrict__ Vt,
                                                   ushort_t* __restrict__ Ob) {
    __shared__ ushort_t Ks[2 * 4096];     // 16 KB: [buf][chunk d/8][s-row 64][8]
    __shared__ ushort_t Vs[2 * 4096];     // 16 KB: [buf][chunk s/8][d-row 64][8]
    __shared__ ushort_t pl[4 * 16 * 80];  // 10 KB: per-wave P, 16 rows x 64 (stride 80)
    const int tid  = threadIdx.x;
    const int lane = tid & 63, wid = tid >> 6;
    const int qn = lane & 15, quad = lane >> 4;
    const int h   = blockIdx.x & 31;
    const int qb  = 31 - (blockIdx.x >> 5);     // heavy first, 0..31 (64-row blocks)
    const int kvb = (h >> 2) * 64;
    const int trow = qb * 64 + wid * 16;
    ushort_t* plw = pl + wid * 16 * 80;
    f32x4 zero = {0.f, 0.f, 0.f, 0.f};

    const ushort_t* qpA = Q + (size_t)(trow + qn) * 2048 + h * 64 + quad * 8;
    const bf16x8 qA0 = ld8(qpA), qA1 = ld8(qpA + 32);

    f32x4 oA[4] = {zero, zero, zero, zero};
    float lA[4] = {0.f, 0.f, 0.f, 0.f};
    const int ntiles = qb + 1;

#define STAGE(s0, buf)                                                         \
    do {                                                                       \
        const ushort_t* kg = Kb + (size_t)((s0) + lane) * 512 + kvb + wid * 8; \
        gl_lds16(kg,      Ks + (buf) * 4096 + wid * 512);                      \
        gl_lds16(kg + 32, Ks + (buf) * 4096 + (wid + 4) * 512);                \
        const ushort_t* vg = Vt + (size_t)(kvb + lane) * 2048 + (s0) + wid * 8;\
        gl_lds16(vg,      Vs + (buf) * 4096 + wid * 512);                      \
        gl_lds16(vg + 32, Vs + (buf) * 4096 + (wid + 4) * 512);                \
    } while (0)

#define COMPUTE(s0, buf)                                                       \
    do {                                                                       \
        f32x4 scA[4];                                                          \
        __builtin_amdgcn_s_setprio(1);                                         \
        _Pragma("unroll")                                                      \
        for (int cb = 0; cb < 4; cb++) {                                       \
            const bf16x8 kf0 = *(const bf16x8*)(Ks + (buf) * 4096 + quad * 512 + (cb * 16 + qn) * 8);       \
            const bf16x8 kf1 = *(const bf16x8*)(Ks + (buf) * 4096 + (quad + 4) * 512 + (cb * 16 + qn) * 8); \
            f32x4 s = mfma16(qA0, kf0, zero); scA[cb] = mfma16(qA1, kf1, s);   \
        }                                                                      \
        __builtin_amdgcn_s_setprio(0);                                         \
        const bool needmask = ((s0) + 63 > trow);                              \
        _Pragma("unroll")                                                      \
        for (int i = 0; i < 4; i++) {                                          \
            const int tA = trow + quad * 4 + i;                                \
            _Pragma("unroll")                                                  \
            for (int cb = 0; cb < 4; cb++) {                                   \
                const int col = (s0) + cb * 16 + qn;                           \
                float vA = scA[cb][i];                                         \
                if (needmask) {                                                \
                    if (col > tA) vA = -INFINITY;                              \
                }                                                              \
                const float pA = fexp2(vA);                                    \
                lA[i] += pA;                                                   \
                plw[(quad * 4 + i) * 80 + cb * 16 + qn] = f2b(pA);             \
            }                                                                  \
        }                                                                      \
        const bf16x8 pfA0 = *(const bf16x8*)(plw + qn * 80 + quad * 8);        \
        const bf16x8 pfA1 = *(const bf16x8*)(plw + qn * 80 + 32 + quad * 8);   \
        __builtin_amdgcn_s_setprio(1);                                         \
        _Pragma("unroll")                                                      \
        for (int dcb = 0; dcb < 4; dcb++) {                                    \
            const bf16x8 vf0 = *(const bf16x8*)(Vs + (buf) * 4096 + quad * 512 + (dcb * 16 + qn) * 8);       \
            const bf16x8 vf1 = *(const bf16x8*)(Vs + (buf) * 4096 + (quad + 4) * 512 + (dcb * 16 + qn) * 8); \
            oA[dcb] = mfma16(pfA0, vf0, oA[dcb]);                              \
            oA[dcb] = mfma16(pfA1, vf1, oA[dcb]);                              \
        }                                                                      \
        __builtin_amdgcn_s_setprio(0);                                         \
    } while (0)

    STAGE(0, 0);
    int t = 0;
    for (; t + 2 <= ntiles; t += 2) {
        __syncthreads();
        STAGE((t + 1) * 64, 1);
        COMPUTE(t * 64, 0);
        __syncthreads();
        if (t + 2 < ntiles) STAGE((t + 2) * 64, 0);
        COMPUTE((t + 1) * 64, 1);
    }
    if (t < ntiles) {                      // odd tail: buf0 already staged
        __syncthreads();
        COMPUTE(t * 64, 0);
    }
#undef STAGE
#undef COMPUTE

    #pragma unroll
    for (int i = 0; i < 4; i++) {
        float sA = lA[i];
        #pragma unroll
        for (int off = 1; off < 16; off <<= 1)
            sA += __shfl_xor(sA, off, 64);
        const float invA = 1.0f / sA;
        ushort_t* obA = Ob + (size_t)(trow + quad * 4 + i) * 2048 + h * 64 + qn;
        obA[0]  = f2b(oA[0][i] * invA);
        obA[16] = f2b(oA[1][i] * invA);
        obA[32] = f2b(oA[2][i] * invA);
        obA[48] = f2b(oA[3][i] * invA);
    }
}

// ---------- launch ----------
extern "C" void kernel_launch(void* const* d_in, const int* in_sizes, int n_in,
                              void* d_out, int out_size, void* d_ws, size_t ws_size,
                              hipStream_t stream) {
    const float* x    = (const float*)d_in[0];
    const float* cosp = (const float*)d_in[1];
    const float* sinp = (const float*)d_in[2];
    // d_in[3] = attention_mask_4d (pure causal; recomputed in-kernel)
    const float* Wq = (const float*)d_in[4];
    const float* Wk = (const float*)d_in[5];
    const float* Wv = (const float*)d_in[6];
    const float* Wo = (const float*)d_in[7];
    char* ws = (char*)d_ws;
    (void)ws_size; (void)in_sizes; (void)n_in; (void)out_size;

    ushort_t* xb    = (ushort_t*)(ws + WS_XB);
    ushort_t* wqkvb = (ushort_t*)(ws + WS_WQKV);
    ushort_t* wob   = (ushort_t*)(ws + WS_WO);
    ushort_t* p0    = (ushort_t*)(ws + WS_P0);
    ushort_t* p1    = (ushort_t*)(ws + WS_P1);
    ushort_t* qbb   = (ushort_t*)(ws + WS_QBB);
    ushort_t* kbb   = (ushort_t*)(ws + WS_KBB);
    ushort_t* vtg   = (ushort_t*)(ws + WS_VTG);
    ushort_t* ab    = (ushort_t*)(ws + WS_AB);
    float*    o0    = (float*)   (ws + WS_O0);
    float*    o1    = (float*)   (ws + WS_O1);

    // 1. convert inputs/weights to bf16 (contiguous dst: xb|wqkvb|wob)
    cvt_all<<<14336, 256, 0, stream>>>(x, Wq, Wk, Wv, Wo, xb);

    // 2. QKV projection split-K=2: 128x64 tiles, 1536 blocks (6/CU)
    gemm_split<1><<<dim3(48, 16, 2), 256, 0, stream>>>(xb, wqkvb, p0, p1, 3072, 2048);

    // 3. fused combine + RoPE(q scale=(1/8)*log2e) + V transpose
    fuse_crv<<<dim3(48, 32), 256, 0, stream>>>(p0, p1, cosp, sinp, qbb, kbb, vtg);

    // 4. attention: 1024 blocks, 64 q-rows each
    attn_kernel<<<1024, 256, 0, stream>>>(qbb, kbb, vtg, ab);

    // 5. O-projection split-K=2: 128x64 tiles, 1024 blocks (4/CU)
    gemm_split<0><<<dim3(32, 16, 2), 256, 0, stream>>>(ab, wob, o0, o1, 2048, 2048);

    // 6. combine partials into fp32 output
    combine_o<<<2048, 256, 0, stream>>>((const float4*)o0, (const float4*)o1,
                                        (float4*)d_out);
}

// Round 8
// 260.174 us; speedup vs baseline: 1.1893x; 1.1893x over previous
//
#include <hip/hip_runtime.h>
#include <math.h>

// ---------- types ----------
typedef __attribute__((ext_vector_type(8))) __bf16 bf16x8;
typedef __attribute__((ext_vector_type(4))) float  f32x4;
typedef unsigned short ushort_t;
typedef unsigned int   uint_t;

static __device__ inline f32x4 mfma16(bf16x8 a, bf16x8 b, f32x4 c) {
    return __builtin_amdgcn_mfma_f32_16x16x32_bf16(a, b, c, 0, 0, 0);
}

static __device__ inline ushort_t f2b(float f) {
    uint_t u = __builtin_bit_cast(uint_t, f);
    u = (u + 0x7FFFu + ((u >> 16) & 1u)) >> 16;
    return (ushort_t)u;
}
static __device__ inline float b2f(ushort_t u) {
    uint_t x = ((uint_t)u) << 16;
    return __builtin_bit_cast(float, x);
}
static __device__ inline bf16x8 ld8(const ushort_t* p) {
    uint4 v = *(const uint4*)p;
    return __builtin_bit_cast(bf16x8, v);
}
static __device__ inline float fexp2(float x) {
#if __has_builtin(__builtin_amdgcn_exp2f)
    return __builtin_amdgcn_exp2f(x);
#else
    return exp2f(x);
#endif
}

// async global->LDS, 16B per lane; LDS dst = base + lane*16 (wave-uniform base!)
static __device__ inline void gl_lds16(const ushort_t* g, ushort_t* l) {
    __builtin_amdgcn_global_load_lds(
        (const __attribute__((address_space(1))) void*)(g),
        (__attribute__((address_space(3))) void*)(l),
        16, 0, 0);
}

// ---------- ws layout (peak = 62,914,560 B, R1 layout) ----------
#define WS_XB     0          //  8 MiB x bf16           [2048,2048]   (dead after QKV gemm)
#define WS_WQKV   8388608    // 12 MiB [Wq;Wk;Wv] bf16  [3072,2048]   (dead after QKV gemm)
#define WS_WO     20971520   //  8 MiB Wo bf16          [2048,2048]
#define WS_P0     29360128   // 12 MiB QKV partial 0 bf16 [2048,3072] (dead after fuse)
#define WS_P1     41943040   // 12 MiB QKV partial 1 bf16 [2048,3072] (dead after fuse)
#define WS_QBB    0          //  8 MiB q roped bf16     (overlays xb)
#define WS_KBB    8388608    //  2 MiB k roped bf16     (overlays wqkvb head)
#define WS_VTG    10485760   //  2 MiB V^T bf16 [512,2048]
#define WS_AB     12582912   //  8 MiB attn out bf16    (ends exactly at WS_WO)
#define WS_O0     29360128   // 16 MiB O partial 0 fp32 (overlays p0)
#define WS_O1     46137344   // 16 MiB O partial 1 fp32 (ends 62914560)

// ---------- fp32 -> bf16 convert for x|Wq|Wk|Wv|Wo (contiguous dst) ----------
__global__ __launch_bounds__(256) void cvt_all(const float* __restrict__ x,
                                               const float* __restrict__ wq,
                                               const float* __restrict__ wk,
                                               const float* __restrict__ wv,
                                               const float* __restrict__ wo,
                                               ushort_t* __restrict__ dst) {
    const size_t i = (size_t)(blockIdx.x * 256 + threadIdx.x) * 4;
    const float* src; size_t off;
    if (i < 4194304)       { src = x;  off = 0; }
    else if (i < 8388608)  { src = wq; off = 4194304; }
    else if (i < 9437184)  { src = wk; off = 8388608; }
    else if (i < 10485760) { src = wv; off = 9437184; }
    else                   { src = wo; off = 10485760; }
    float4 v = *(const float4*)(src + (i - off));
    ushort4 o;
    o.x = f2b(v.x); o.y = f2b(v.y); o.z = f2b(v.z); o.w = f2b(v.w);
    *(ushort4*)(dst + i) = o;
}

// ---------- 256x256 8-phase GEMM (T2 swizzle + T3/T4 counted vmcnt + T5) ----------
// R11 defensive revision vs the R6/R7 submit (template-exact, m201 recipe):
//   * prologue drains vmcnt(0) (ledger re-verified: steady state 4 in flight at
//     each tile boundary, drained only entering the final tile);
//   * each phase: barrier -> s_waitcnt lgkmcnt(0) -> sched_barrier(0) (rule #18)
//     -> setprio(1) -> 16 MFMA -> setprio(0) -> barrier.
// Geometry: 8 waves (512 thr), BK=64, LDS 128 KiB = 2 buf x {A 32K | B 32K},
// each operand as two 128x64 halves. Phase p of a tile computes C-quadrant
// (qr,qc)=(p>>1,p&1); wave (w>>2, w&3) owns 64x32 of it. Half-use: A0 p0,p1 /
// B0 p0,p2 / B1 p1,p3 / A1 p2,p3. Stage stream per tile: p0:B1(t+1) p1:A1(t+1)
// p2:A0(t+2) p3:B0(t+2) — each half overwritten >=1 full barrier-pair after its
// last read. Boundary vmcnt(4) at p3 (never 0 mid-loop).
// T2 swizzle: LDS chunk c of row r holds global chunk c^(r&7); staging
// pre-swizzles the GLOBAL source chunk (linear LDS dest, rule #21); reads XOR
// the same -> stride-128B fragment reads conflict-free.
template <int OUTB>
__global__ __launch_bounds__(512, 2) void gemm256(const ushort_t* __restrict__ A,
                                                  const ushort_t* __restrict__ Bt,
                                                  void* __restrict__ C0,
                                                  void* __restrict__ C1,
                                                  int N, int K) {
    __shared__ ushort_t lds[65536];   // 128 KiB
    const int tid  = threadIdx.x;
    const int lane = tid & 63, w = tid >> 6;
    const int qn = lane & 15, quad = lane >> 4;
    const long m0 = (long)blockIdx.y * 256;
    const long n0 = (long)blockIdx.x * 256;
    const int kh   = K >> 1;
    const int kbeg = blockIdx.z * kh;
    const int NT   = kh >> 6;                  // K-tiles per block; even, >=4
    void* Cout = blockIdx.z ? C1 : C0;
    ushort_t* ldsp = lds;

    // staging: thread covers row srow (+64 for 2nd load) of a 128-row half,
    // 16B chunk scol pre-swizzled so linear LDS dest yields swizzled layout.
    const int srow = w * 8 + (lane >> 3);
    const int scol = ((lane & 7) ^ (lane >> 3)) * 8;
    const ushort_t* gA = A  + (m0 + srow) * (size_t)K + kbeg + scol;
    const ushort_t* gB = Bt + (n0 + srow) * (size_t)K + kbeg + scol;

    // fragment-read offsets (shorts). half layout: [row 128][64 k-shorts].
    const int aRow = ((w >> 2) * 64 + qn) * 64;
    const int bRow = ((w & 3) * 32 + qn) * 64;
    const int sw0 = ((quad * 16)      ^ ((qn & 7) << 4)) >> 1;   // ks=0
    const int sw1 = ((64 + quad * 16) ^ ((qn & 7) << 4)) >> 1;   // ks=1

#define STG_A(t, h, buf)                                                       \
    do { if ((t) < NT) {                                                       \
        const ushort_t* g = gA + (size_t)(h) * 128 * K + (t) * 64;             \
        ushort_t* d = ldsp + (buf) * 32768 + (h) * 8192 + w * 512;             \
        gl_lds16(g, d);                                                        \
        gl_lds16(g + 64 * (size_t)K, d + 4096);                                \
    } } while (0)
#define STG_B(t, h, buf)                                                       \
    do { if ((t) < NT) {                                                       \
        const ushort_t* g = gB + (size_t)(h) * 128 * K + (t) * 64;             \
        ushort_t* d = ldsp + (buf) * 32768 + 16384 + (h) * 8192 + w * 512;     \
        gl_lds16(g, d);                                                        \
        gl_lds16(g + 64 * (size_t)K, d + 4096);                                \
    } } while (0)

#define PHASE(cb, p, qr, qc, STAGE, BOUND)                                     \
    do {                                                                       \
        const ushort_t* bA = ldsp + (cb) * 32768 + (qr) * 8192;                \
        const ushort_t* bB = ldsp + (cb) * 32768 + 16384 + (qc) * 8192;        \
        bf16x8 af[4][2], bv[2][2];                                             \
        _Pragma("unroll")                                                      \
        for (int mi = 0; mi < 4; mi++) {                                       \
            af[mi][0] = *(const bf16x8*)(bA + aRow + mi * 1024 + sw0);         \
            af[mi][1] = *(const bf16x8*)(bA + aRow + mi * 1024 + sw1);         \
        }                                                                      \
        _Pragma("unroll")                                                      \
        for (int nj = 0; nj < 2; nj++) {                                       \
            bv[nj][0] = *(const bf16x8*)(bB + bRow + nj * 1024 + sw0);         \
            bv[nj][1] = *(const bf16x8*)(bB + bRow + nj * 1024 + sw1);         \
        }                                                                      \
        asm volatile("" ::: "memory");  /* pin reads above the stage */        \
        STAGE;                                                                 \
        BOUND;                                                                 \
        __builtin_amdgcn_s_barrier();                                          \
        asm volatile("s_waitcnt lgkmcnt(0)" ::: "memory");                     \
        __builtin_amdgcn_sched_barrier(0);                                     \
        __builtin_amdgcn_s_setprio(1);                                         \
        _Pragma("unroll")                                                      \
        for (int mi = 0; mi < 4; mi++)                                         \
            _Pragma("unroll")                                                  \
            for (int nj = 0; nj < 2; nj++) {                                   \
                acc[p][mi][nj] = mfma16(af[mi][0], bv[nj][0], acc[p][mi][nj]); \
                acc[p][mi][nj] = mfma16(af[mi][1], bv[nj][1], acc[p][mi][nj]); \
            }                                                                  \
        __builtin_amdgcn_s_setprio(0);                                         \
        __builtin_amdgcn_s_barrier();                                          \
    } while (0)

    f32x4 acc[4][4][2];
    f32x4 zero = {0.f, 0.f, 0.f, 0.f};
    #pragma unroll
    for (int p = 0; p < 4; p++)
        #pragma unroll
        for (int mi = 0; mi < 4; mi++)
            #pragma unroll
            for (int nj = 0; nj < 2; nj++) acc[p][mi][nj] = zero;

    // prologue: stage t0 fully + t1 A0,B0, then FULL drain (defensive; the
    // counted-vmcnt pipeline starts from a clean 0-outstanding state).
    STG_A(0, 0, 0); STG_B(0, 0, 0); STG_B(0, 1, 0); STG_A(0, 1, 0);
    STG_A(1, 0, 1); STG_B(1, 0, 1);
    asm volatile("s_waitcnt vmcnt(0)" ::: "memory");
    __builtin_amdgcn_s_barrier();

    // Ledger (drain-0 prologue): entering even tile t2: outstanding = 0 (t2=0)
    // or {t2:A0,B0}=4. Even tile stages +4 -> boundary vmcnt(4) retires the
    // previous-staged 4 => buf1 tile fully landed; outstanding {t2+2:A0,B0}.
    // Odd tile symmetric. At t2==NT-2: stages of t2+2 skipped; vmcnt(0) drains
    // B1/A1(NT-1) => final tile landed; last odd boundary vmcnt(4) is a no-op.
    for (int t2 = 0; t2 < NT; t2 += 2) {
        // even tile t2 (buf 0)
        PHASE(0, 0, 0, 0, STG_B(t2 + 1, 1, 1), (void)0);
        PHASE(0, 1, 0, 1, STG_A(t2 + 1, 1, 1), (void)0);
        PHASE(0, 2, 1, 0, STG_A(t2 + 2, 0, 0), (void)0);
        PHASE(0, 3, 1, 1, STG_B(t2 + 2, 0, 0),
              if (t2 == NT - 2) { asm volatile("s_waitcnt vmcnt(0)" ::: "memory"); }
              else              { asm volatile("s_waitcnt vmcnt(4)" ::: "memory"); });
        // odd tile t2+1 (buf 1)
        PHASE(1, 0, 0, 0, STG_B(t2 + 2, 1, 0), (void)0);
        PHASE(1, 1, 0, 1, STG_A(t2 + 2, 1, 0), (void)0);
        PHASE(1, 2, 1, 0, STG_A(t2 + 3, 0, 1), (void)0);
        PHASE(1, 3, 1, 1, STG_B(t2 + 3, 0, 1),
              asm volatile("s_waitcnt vmcnt(4)" ::: "memory"););
    }
#undef PHASE
#undef STG_A
#undef STG_B

    #pragma unroll
    for (int p = 0; p < 4; p++) {
        const int qr = p >> 1, qc = p & 1;
        #pragma unroll
        for (int mi = 0; mi < 4; mi++)
            #pragma unroll
            for (int nj = 0; nj < 2; nj++) {
                const long row0 = m0 + qr * 128 + (w >> 2) * 64 + mi * 16 + quad * 4;
                const long col  = n0 + qc * 128 + (w & 3) * 32 + nj * 16 + qn;
                #pragma unroll
                for (int r = 0; r < 4; r++) {
                    if (OUTB)
                        ((ushort_t*)Cout)[(row0 + r) * N + col] = f2b(acc[p][mi][nj][r]);
                    else
                        ((float*)Cout)[(row0 + r) * N + col] = acc[p][mi][nj][r];
                }
            }
    }
}

// ---------- fused combine + RoPE + V-transpose (R1 verbatim) ----------
__global__ __launch_bounds__(256) void fuse_crv(const ushort_t* __restrict__ p0,
                                                const ushort_t* __restrict__ p1,
                                                const float* __restrict__ cs,
                                                const float* __restrict__ sn,
                                                ushort_t* __restrict__ qd,
                                                ushort_t* __restrict__ kd,
                                                ushort_t* __restrict__ vt) {
    __shared__ ushort_t tl[64][65];
    const int cx = blockIdx.x;               // 0..47
    const int ty = blockIdx.y;               // 0..31
    const int r  = threadIdx.x >> 2;         // 0..63
    const int c0 = (threadIdx.x & 3) << 4;   // 0,16,32,48
    const int t  = ty * 64 + r;
    const size_t base = (size_t)t * 3072 + cx * 64;

    if (cx < 40) {                           // q or k: combine + rope
        const int cp = c0 ^ 32;
        float own[16], par[16];
        #pragma unroll
        for (int jj = 0; jj < 2; jj++) {
            uint4 a = *(const uint4*)(p0 + base + c0 + jj * 8);
            uint4 b = *(const uint4*)(p1 + base + c0 + jj * 8);
            uint4 c = *(const uint4*)(p0 + base + cp + jj * 8);
            uint4 d = *(const uint4*)(p1 + base + cp + jj * 8);
            const ushort_t* pa = (const ushort_t*)&a;
            const ushort_t* pb = (const ushort_t*)&b;
            const ushort_t* pc = (const ushort_t*)&c;
            const ushort_t* pd = (const ushort_t*)&d;
            #pragma unroll
            for (int e = 0; e < 8; e++) {
                own[jj * 8 + e] = b2f(pa[e]) + b2f(pb[e]);
                par[jj * 8 + e] = b2f(pc[e]) + b2f(pd[e]);
            }
        }
        float cs16[16], sn16[16];
        #pragma unroll
        for (int jj = 0; jj < 4; jj++) {
            float4 c4 = *(const float4*)(cs + (size_t)t * 64 + c0 + jj * 4);
            float4 s4 = *(const float4*)(sn + (size_t)t * 64 + c0 + jj * 4);
            cs16[jj * 4 + 0] = c4.x; cs16[jj * 4 + 1] = c4.y;
            cs16[jj * 4 + 2] = c4.z; cs16[jj * 4 + 3] = c4.w;
            sn16[jj * 4 + 0] = s4.x; sn16[jj * 4 + 1] = s4.y;
            sn16[jj * 4 + 2] = s4.z; sn16[jj * 4 + 3] = s4.w;
        }
        const float scale = (cx < 32) ? 0.18033688f : 1.0f;  // q: (1/8)*log2e
        union { ushort_t u[16]; uint4 v[2]; } o;
        #pragma unroll
        for (int j = 0; j < 16; j++) {
            const int d = c0 + j;
            const float pr = (d < 32) ? -par[j] : par[j];
            o.u[j] = f2b((own[j] * cs16[j] + pr * sn16[j]) * scale);
        }
        if (cx < 32) {
            ushort_t* dst = qd + (size_t)t * 2048 + cx * 64 + c0;
            *(uint4*)dst = o.v[0]; *(uint4*)(dst + 8) = o.v[1];
        } else {
            ushort_t* dst = kd + (size_t)t * 512 + (cx - 32) * 64 + c0;
            *(uint4*)dst = o.v[0]; *(uint4*)(dst + 8) = o.v[1];
        }
    } else {                                 // v: combine + transpose via LDS
        #pragma unroll
        for (int jj = 0; jj < 2; jj++) {
            uint4 a = *(const uint4*)(p0 + base + c0 + jj * 8);
            uint4 b = *(const uint4*)(p1 + base + c0 + jj * 8);
            const ushort_t* pa = (const ushort_t*)&a;
            const ushort_t* pb = (const ushort_t*)&b;
            #pragma unroll
            for (int e = 0; e < 8; e++)
                tl[r][c0 + jj * 8 + e] = f2b(b2f(pa[e]) + b2f(pb[e]));
        }
        __syncthreads();
        const int rr  = threadIdx.x >> 3;        // 0..31
        const int cc8 = (threadIdx.x & 7) * 8;
        const int db = (cx - 40) * 64, tb = ty * 64;
        #pragma unroll
        for (int h = 0; h < 2; h++) {
            const int d = rr + h * 32;
            ushort4 o0, o1;
            o0.x = tl[cc8 + 0][d]; o0.y = tl[cc8 + 1][d];
            o0.z = tl[cc8 + 2][d]; o0.w = tl[cc8 + 3][d];
            o1.x = tl[cc8 + 4][d]; o1.y = tl[cc8 + 5][d];
            o1.z = tl[cc8 + 6][d]; o1.w = tl[cc8 + 7][d];
            *(ushort4*)(vt + (size_t)(db + d) * 2048 + tb + cc8)     = o0;
            *(ushort4*)(vt + (size_t)(db + d) * 2048 + tb + cc8 + 4) = o1;
        }
    }
}

// ---------- combine O partials -> fp32 out ----------
__global__ __launch_bounds__(256) void combine_o(const float4* __restrict__ s0,
                                                 const float4* __restrict__ s1,
                                                 float4* __restrict__ out) {
    for (int i = blockIdx.x * 256 + threadIdx.x; i < 1048576; i += 2048 * 256) {
        float4 a = s0[i], b = s1[i];
        float4 r; r.x = a.x + b.x; r.y = a.y + b.y; r.z = a.z + b.z; r.w = a.w + b.w;
        out[i] = r;
    }
}

// ---------- flash attention, causal, GQA G=4 (R2 version: 64 q-rows + setprio) ----------
__global__ __launch_bounds__(256) void attn_kernel(const ushort_t* __restrict__ Q,
                                                   const ushort_t* __restrict__ Kb,
                                                   const ushort_t* __restrict__ Vt,
                                                   ushort_t* __restrict__ Ob) {
    __shared__ ushort_t Ks[2 * 4096];     // 16 KB: [buf][chunk d/8][s-row 64][8]
    __shared__ ushort_t Vs[2 * 4096];     // 16 KB: [buf][chunk s/8][d-row 64][8]
    __shared__ ushort_t pl[4 * 16 * 80];  // 10 KB: per-wave P, 16 rows x 64 (stride 80)
    const int tid  = threadIdx.x;
    const int lane = tid & 63, wid = tid >> 6;
    const int qn = lane & 15, quad = lane >> 4;
    const int h   = blockIdx.x & 31;
    const int qb  = 31 - (blockIdx.x >> 5);     // heavy first, 0..31 (64-row blocks)
    const int kvb = (h >> 2) * 64;
    const int trow = qb * 64 + wid * 16;
    ushort_t* plw = pl + wid * 16 * 80;
    f32x4 zero = {0.f, 0.f, 0.f, 0.f};

    const ushort_t* qpA = Q + (size_t)(trow + qn) * 2048 + h * 64 + quad * 8;
    const bf16x8 qA0 = ld8(qpA), qA1 = ld8(qpA + 32);

    f32x4 oA[4] = {zero, zero, zero, zero};
    float lA[4] = {0.f, 0.f, 0.f, 0.f};
    const int ntiles = qb + 1;

#define STAGE(s0, buf)                                                         \
    do {                                                                       \
        const ushort_t* kg = Kb + (size_t)((s0) + lane) * 512 + kvb + wid * 8; \
        gl_lds16(kg,      Ks + (buf) * 4096 + wid * 512);                      \
        gl_lds16(kg + 32, Ks + (buf) * 4096 + (wid + 4) * 512);                \
        const ushort_t* vg = Vt + (size_t)(kvb + lane) * 2048 + (s0) + wid * 8;\
        gl_lds16(vg,      Vs + (buf) * 4096 + wid * 512);                      \
        gl_lds16(vg + 32, Vs + (buf) * 4096 + (wid + 4) * 512);                \
    } while (0)

#define COMPUTE(s0, buf)                                                       \
    do {                                                                       \
        f32x4 scA[4];                                                          \
        __builtin_amdgcn_s_setprio(1);                                         \
        _Pragma("unroll")                                                      \
        for (int cb = 0; cb < 4; cb++) {                                       \
            const bf16x8 kf0 = *(const bf16x8*)(Ks + (buf) * 4096 + quad * 512 + (cb * 16 + qn) * 8);       \
            const bf16x8 kf1 = *(const bf16x8*)(Ks + (buf) * 4096 + (quad + 4) * 512 + (cb * 16 + qn) * 8); \
            f32x4 s = mfma16(qA0, kf0, zero); scA[cb] = mfma16(qA1, kf1, s);   \
        }                                                                      \
        __builtin_amdgcn_s_setprio(0);                                         \
        const bool needmask = ((s0) + 63 > trow);                              \
        _Pragma("unroll")                                                      \
        for (int i = 0; i < 4; i++) {                                          \
            const int tA = trow + quad * 4 + i;                                \
            _Pragma("unroll")                                                  \
            for (int cb = 0; cb < 4; cb++) {                                   \
                const int col = (s0) + cb * 16 + qn;                           \
                float vA = scA[cb][i];                                         \
                if (needmask) {                                                \
                    if (col > tA) vA = -INFINITY;                              \
                }                                                              \
                const float pA = fexp2(vA);                                    \
                lA[i] += pA;                                                   \
                plw[(quad * 4 + i) * 80 + cb * 16 + qn] = f2b(pA);             \
            }                                                                  \
        }                                                                      \
        const bf16x8 pfA0 = *(const bf16x8*)(plw + qn * 80 + quad * 8);        \
        const bf16x8 pfA1 = *(const bf16x8*)(plw + qn * 80 + 32 + quad * 8);   \
        __builtin_amdgcn_s_setprio(1);                                         \
        _Pragma("unroll")                                                      \
        for (int dcb = 0; dcb < 4; dcb++) {                                    \
            const bf16x8 vf0 = *(const bf16x8*)(Vs + (buf) * 4096 + quad * 512 + (dcb * 16 + qn) * 8);       \
            const bf16x8 vf1 = *(const bf16x8*)(Vs + (buf) * 4096 + (quad + 4) * 512 + (dcb * 16 + qn) * 8); \
            oA[dcb] = mfma16(pfA0, vf0, oA[dcb]);                              \
            oA[dcb] = mfma16(pfA1, vf1, oA[dcb]);                              \
        }                                                                      \
        __builtin_amdgcn_s_setprio(0);                                         \
    } while (0)

    STAGE(0, 0);
    int t = 0;
    for (; t + 2 <= ntiles; t += 2) {
        __syncthreads();
        STAGE((t + 1) * 64, 1);
        COMPUTE(t * 64, 0);
        __syncthreads();
        if (t + 2 < ntiles) STAGE((t + 2) * 64, 0);
        COMPUTE((t + 1) * 64, 1);
    }
    if (t < ntiles) {                      // odd tail: buf0 already staged
        __syncthreads();
        COMPUTE(t * 64, 0);
    }
#undef STAGE
#undef COMPUTE

    #pragma unroll
    for (int i = 0; i < 4; i++) {
        float sA = lA[i];
        #pragma unroll
        for (int off = 1; off < 16; off <<= 1)
            sA += __shfl_xor(sA, off, 64);
        const float invA = 1.0f / sA;
        ushort_t* obA = Ob + (size_t)(trow + quad * 4 + i) * 2048 + h * 64 + qn;
        obA[0]  = f2b(oA[0][i] * invA);
        obA[16] = f2b(oA[1][i] * invA);
        obA[32] = f2b(oA[2][i] * invA);
        obA[48] = f2b(oA[3][i] * invA);
    }
}

// ---------- launch ----------
extern "C" void kernel_launch(void* const* d_in, const int* in_sizes, int n_in,
                              void* d_out, int out_size, void* d_ws, size_t ws_size,
                              hipStream_t stream) {
    const float* x    = (const float*)d_in[0];
    const float* cosp = (const float*)d_in[1];
    const float* sinp = (const float*)d_in[2];
    // d_in[3] = attention_mask_4d (pure causal; recomputed in-kernel)
    const float* Wq = (const float*)d_in[4];
    const float* Wk = (const float*)d_in[5];
    const float* Wv = (const float*)d_in[6];
    const float* Wo = (const float*)d_in[7];
    char* ws = (char*)d_ws;
    (void)ws_size; (void)in_sizes; (void)n_in; (void)out_size;

    ushort_t* xb    = (ushort_t*)(ws + WS_XB);
    ushort_t* wqkvb = (ushort_t*)(ws + WS_WQKV);
    ushort_t* wob   = (ushort_t*)(ws + WS_WO);
    ushort_t* p0    = (ushort_t*)(ws + WS_P0);
    ushort_t* p1    = (ushort_t*)(ws + WS_P1);
    ushort_t* qbb   = (ushort_t*)(ws + WS_QBB);
    ushort_t* kbb   = (ushort_t*)(ws + WS_KBB);
    ushort_t* vtg   = (ushort_t*)(ws + WS_VTG);
    ushort_t* ab    = (ushort_t*)(ws + WS_AB);
    float*    o0    = (float*)   (ws + WS_O0);
    float*    o1    = (float*)   (ws + WS_O1);

    // 1. convert inputs/weights to bf16 (contiguous dst: xb|wqkvb|wob)
    cvt_all<<<14336, 256, 0, stream>>>(x, Wq, Wk, Wv, Wo, xb);

    // 2. QKV projection split-K=2: 256^2 8-phase, 192 blocks
    gemm256<1><<<dim3(12, 8, 2), 512, 0, stream>>>(xb, wqkvb, p0, p1, 3072, 2048);

    // 3. fused combine + RoPE(q scale=(1/8)*log2e) + V transpose
    fuse_crv<<<dim3(48, 32), 256, 0, stream>>>(p0, p1, cosp, sinp, qbb, kbb, vtg);

    // 4. attention: 1024 blocks, 64 q-rows each
    attn_kernel<<<1024, 256, 0, stream>>>(qbb, kbb, vtg, ab);

    // 5. O-projection split-K=2: 256^2 8-phase, 128 blocks
    gemm256<0><<<dim3(8, 8, 2), 512, 0, stream>>>(ab, wob, o0, o1, 2048, 2048);

    // 6. combine partials into fp32 output
    combine_o<<<2048, 256, 0, stream>>>((const float4*)o0, (const float4*)o1,
                                        (float4*)d_out);
}

// Round 9
// 254.636 us; speedup vs baseline: 1.2152x; 1.0217x over previous
//
#include <hip/hip_runtime.h>
#include <math.h>

// ---------- types ----------
typedef __attribute__((ext_vector_type(8))) __bf16 bf16x8;
typedef __attribute__((ext_vector_type(4))) float  f32x4;
typedef unsigned short ushort_t;
typedef unsigned int   uint_t;

static __device__ inline f32x4 mfma16(bf16x8 a, bf16x8 b, f32x4 c) {
    return __builtin_amdgcn_mfma_f32_16x16x32_bf16(a, b, c, 0, 0, 0);
}

// R12: native RNE cast (1 VALU op: v_cvt_pk_bf16_f32) — bit-identical to the
// old add-0x7FFF emulation (~4 ops) for finite values.
static __device__ inline ushort_t f2b(float f) {
    return __builtin_bit_cast(ushort_t, (__bf16)f);
}
static __device__ inline float b2f(ushort_t u) {
    uint_t x = ((uint_t)u) << 16;
    return __builtin_bit_cast(float, x);
}
static __device__ inline bf16x8 ld8(const ushort_t* p) {
    uint4 v = *(const uint4*)p;
    return __builtin_bit_cast(bf16x8, v);
}
static __device__ inline float fexp2(float x) {
#if __has_builtin(__builtin_amdgcn_exp2f)
    return __builtin_amdgcn_exp2f(x);
#else
    return exp2f(x);
#endif
}

// async global->LDS, 16B per lane; LDS dst = base + lane*16 (wave-uniform base!)
static __device__ inline void gl_lds16(const ushort_t* g, ushort_t* l) {
    __builtin_amdgcn_global_load_lds(
        (const __attribute__((address_space(1))) void*)(g),
        (__attribute__((address_space(3))) void*)(l),
        16, 0, 0);
}

// ---------- ws layout (peak = 62,914,560 B, R1 layout) ----------
#define WS_XB     0          //  8 MiB x bf16           [2048,2048]   (dead after QKV gemm)
#define WS_WQKV   8388608    // 12 MiB [Wq;Wk;Wv] bf16  [3072,2048]   (dead after QKV gemm)
#define WS_WO     20971520   //  8 MiB Wo bf16          [2048,2048]
#define WS_P0     29360128   // 12 MiB QKV partial 0 bf16 [2048,3072] (dead after fuse)
#define WS_P1     41943040   // 12 MiB QKV partial 1 bf16 [2048,3072] (dead after fuse)
#define WS_QBB    0          //  8 MiB q roped bf16     (overlays xb)
#define WS_KBB    8388608    //  2 MiB k roped bf16     (overlays wqkvb head)
#define WS_VTG    10485760   //  2 MiB V^T bf16 [512,2048]
#define WS_AB     12582912   //  8 MiB attn out bf16    (ends exactly at WS_WO)
#define WS_O0     29360128   // 16 MiB O partial 0 fp32 (overlays p0)
#define WS_O1     46137344   // 16 MiB O partial 1 fp32 (ends 62914560)

// ---------- fp32 -> bf16 convert for x|Wq|Wk|Wv|Wo (contiguous dst) ----------
__global__ __launch_bounds__(256) void cvt_all(const float* __restrict__ x,
                                               const float* __restrict__ wq,
                                               const float* __restrict__ wk,
                                               const float* __restrict__ wv,
                                               const float* __restrict__ wo,
                                               ushort_t* __restrict__ dst) {
    const size_t i = (size_t)(blockIdx.x * 256 + threadIdx.x) * 4;
    const float* src; size_t off;
    if (i < 4194304)       { src = x;  off = 0; }
    else if (i < 8388608)  { src = wq; off = 4194304; }
    else if (i < 9437184)  { src = wk; off = 8388608; }
    else if (i < 10485760) { src = wv; off = 9437184; }
    else                   { src = wo; off = 10485760; }
    float4 v = *(const float4*)(src + (i - off));
    ushort4 o;
    o.x = f2b(v.x); o.y = f2b(v.y); o.z = f2b(v.z); o.w = f2b(v.w);
    *(ushort4*)(dst + i) = o;
}

// ---------- 256x256 8-phase GEMM (proven R8; QKV only) ----------
// 8 waves, BK=64, LDS 128 KiB = 2 buf x {A 32K | B 32K}, each as two 128x64
// halves. Phase p of a tile computes C-quadrant (p>>1,p&1); wave (w>>2,w&3)
// owns 64x32. Half-use: A0 p0,p1 / B0 p0,p2 / B1 p1,p3 / A1 p2,p3. Stage
// stream: p0:B1(t+1) p1:A1(t+1) p2:A0(t+2) p3:B0(t+2). Boundary vmcnt(4);
// vmcnt(0) only entering the final tile. T2 swizzle via pre-swizzled global
// source + XOR'd reads.
template <int OUTB>
__global__ __launch_bounds__(512, 2) void gemm256(const ushort_t* __restrict__ A,
                                                  const ushort_t* __restrict__ Bt,
                                                  void* __restrict__ C0,
                                                  void* __restrict__ C1,
                                                  int N, int K) {
    __shared__ ushort_t lds[65536];   // 128 KiB
    const int tid  = threadIdx.x;
    const int lane = tid & 63, w = tid >> 6;
    const int qn = lane & 15, quad = lane >> 4;
    const long m0 = (long)blockIdx.y * 256;
    const long n0 = (long)blockIdx.x * 256;
    const int kh   = K >> 1;
    const int kbeg = blockIdx.z * kh;
    const int NT   = kh >> 6;                  // even, >=4
    void* Cout = blockIdx.z ? C1 : C0;
    ushort_t* ldsp = lds;

    const int srow = w * 8 + (lane >> 3);
    const int scol = ((lane & 7) ^ (lane >> 3)) * 8;
    const ushort_t* gA = A  + (m0 + srow) * (size_t)K + kbeg + scol;
    const ushort_t* gB = Bt + (n0 + srow) * (size_t)K + kbeg + scol;

    const int aRow = ((w >> 2) * 64 + qn) * 64;
    const int bRow = ((w & 3) * 32 + qn) * 64;
    const int sw0 = ((quad * 16)      ^ ((qn & 7) << 4)) >> 1;   // ks=0
    const int sw1 = ((64 + quad * 16) ^ ((qn & 7) << 4)) >> 1;   // ks=1

#define STG_A(t, h, buf)                                                       \
    do { if ((t) < NT) {                                                       \
        const ushort_t* g = gA + (size_t)(h) * 128 * K + (t) * 64;             \
        ushort_t* d = ldsp + (buf) * 32768 + (h) * 8192 + w * 512;             \
        gl_lds16(g, d);                                                        \
        gl_lds16(g + 64 * (size_t)K, d + 4096);                                \
    } } while (0)
#define STG_B(t, h, buf)                                                       \
    do { if ((t) < NT) {                                                       \
        const ushort_t* g = gB + (size_t)(h) * 128 * K + (t) * 64;             \
        ushort_t* d = ldsp + (buf) * 32768 + 16384 + (h) * 8192 + w * 512;     \
        gl_lds16(g, d);                                                        \
        gl_lds16(g + 64 * (size_t)K, d + 4096);                                \
    } } while (0)

#define PHASE(cb, p, qr, qc, STAGE, BOUND)                                     \
    do {                                                                       \
        const ushort_t* bA = ldsp + (cb) * 32768 + (qr) * 8192;                \
        const ushort_t* bB = ldsp + (cb) * 32768 + 16384 + (qc) * 8192;        \
        bf16x8 af[4][2], bv[2][2];                                             \
        _Pragma("unroll")                                                      \
        for (int mi = 0; mi < 4; mi++) {                                       \
            af[mi][0] = *(const bf16x8*)(bA + aRow + mi * 1024 + sw0);         \
            af[mi][1] = *(const bf16x8*)(bA + aRow + mi * 1024 + sw1);         \
        }                                                                      \
        _Pragma("unroll")                                                      \
        for (int nj = 0; nj < 2; nj++) {                                       \
            bv[nj][0] = *(const bf16x8*)(bB + bRow + nj * 1024 + sw0);         \
            bv[nj][1] = *(const bf16x8*)(bB + bRow + nj * 1024 + sw1);         \
        }                                                                      \
        asm volatile("" ::: "memory");  /* pin reads above the stage */        \
        STAGE;                                                                 \
        BOUND;                                                                 \
        __builtin_amdgcn_s_barrier();                                          \
        asm volatile("s_waitcnt lgkmcnt(0)" ::: "memory");                     \
        __builtin_amdgcn_sched_barrier(0);                                     \
        __builtin_amdgcn_s_setprio(1);                                         \
        _Pragma("unroll")                                                      \
        for (int mi = 0; mi < 4; mi++)                                         \
            _Pragma("unroll")                                                  \
            for (int nj = 0; nj < 2; nj++) {                                   \
                acc[p][mi][nj] = mfma16(af[mi][0], bv[nj][0], acc[p][mi][nj]); \
                acc[p][mi][nj] = mfma16(af[mi][1], bv[nj][1], acc[p][mi][nj]); \
            }                                                                  \
        __builtin_amdgcn_s_setprio(0);                                         \
        __builtin_amdgcn_s_barrier();                                          \
    } while (0)

    f32x4 acc[4][4][2];
    f32x4 zero = {0.f, 0.f, 0.f, 0.f};
    #pragma unroll
    for (int p = 0; p < 4; p++)
        #pragma unroll
        for (int mi = 0; mi < 4; mi++)
            #pragma unroll
            for (int nj = 0; nj < 2; nj++) acc[p][mi][nj] = zero;

    STG_A(0, 0, 0); STG_B(0, 0, 0); STG_B(0, 1, 0); STG_A(0, 1, 0);
    STG_A(1, 0, 1); STG_B(1, 0, 1);
    asm volatile("s_waitcnt vmcnt(0)" ::: "memory");
    __builtin_amdgcn_s_barrier();

    for (int t2 = 0; t2 < NT; t2 += 2) {
        PHASE(0, 0, 0, 0, STG_B(t2 + 1, 1, 1), (void)0);
        PHASE(0, 1, 0, 1, STG_A(t2 + 1, 1, 1), (void)0);
        PHASE(0, 2, 1, 0, STG_A(t2 + 2, 0, 0), (void)0);
        PHASE(0, 3, 1, 1, STG_B(t2 + 2, 0, 0),
              if (t2 == NT - 2) { asm volatile("s_waitcnt vmcnt(0)" ::: "memory"); }
              else              { asm volatile("s_waitcnt vmcnt(4)" ::: "memory"); });
        PHASE(1, 0, 0, 0, STG_B(t2 + 2, 1, 0), (void)0);
        PHASE(1, 1, 0, 1, STG_A(t2 + 2, 1, 0), (void)0);
        PHASE(1, 2, 1, 0, STG_A(t2 + 3, 0, 1), (void)0);
        PHASE(1, 3, 1, 1, STG_B(t2 + 3, 0, 1),
              asm volatile("s_waitcnt vmcnt(4)" ::: "memory"););
    }
#undef PHASE
#undef STG_A
#undef STG_B

    #pragma unroll
    for (int p = 0; p < 4; p++) {
        const int qr = p >> 1, qc = p & 1;
        #pragma unroll
        for (int mi = 0; mi < 4; mi++)
            #pragma unroll
            for (int nj = 0; nj < 2; nj++) {
                const long row0 = m0 + qr * 128 + (w >> 2) * 64 + mi * 16 + quad * 4;
                const long col  = n0 + qc * 128 + (w & 3) * 32 + nj * 16 + qn;
                #pragma unroll
                for (int r = 0; r < 4; r++) {
                    if (OUTB)
                        ((ushort_t*)Cout)[(row0 + r) * N + col] = f2b(acc[p][mi][nj][r]);
                    else
                        ((float*)Cout)[(row0 + r) * N + col] = acc[p][mi][nj][r];
                }
            }
    }
}

// ---------- 256x128 8-phase GEMM (O-projection; R12) ----------
// Same schedule skeleton as gemm256, BN halved so the grid reaches 256 blocks
// = 1/CU (the 256^2 O-proj grid was 128 blocks -> half the chip idle).
// LDS 96 KiB = 2 buf x {A0 16K | A1 16K | B0 8K | B1 8K}. B-halves are 64
// cols (1 gl_lds each). Phases p: (qr,qc)=(p>>1,p&1): (A0,B0)(A0,B1)(A1,B0)
// (A1,B1); wave (wm=w>>1, wn=w&1) owns 32x32 per phase; 8 MFMA/phase.
// Stage stream: p0:B1(t+1,+1) p1:A1(t+1,+2) p2:A0(t+2,+2) p3:B0(t+2,+1).
// Ledger (drain-0 prologue): 6 in flight at even-tile boundary, 9 at odd ->
// boundary vmcnt(3) retires exactly the next tile's halves; vmcnt(0) entering
// the final tile; last boundary no-op. Half overwritten >=1 barrier-pair
// after its last read (A0 last p1/staged p2; B0 last p2/staged p3).
__global__ __launch_bounds__(512, 2) void gemm_op(const ushort_t* __restrict__ A,
                                                  const ushort_t* __restrict__ Bt,
                                                  float* __restrict__ C0,
                                                  float* __restrict__ C1,
                                                  int N, int K) {
    __shared__ ushort_t lds[49152];   // 96 KiB
    const int tid  = threadIdx.x;
    const int lane = tid & 63, w = tid >> 6;
    const int qn = lane & 15, quad = lane >> 4;
    const long m0 = (long)blockIdx.y * 256;
    const long n0 = (long)blockIdx.x * 128;
    const int kh   = K >> 1;
    const int kbeg = blockIdx.z * kh;
    const int NT   = kh >> 6;                  // even, >=4 (16 here)
    float* Cout = blockIdx.z ? C1 : C0;
    ushort_t* ldsp = lds;

    // A staging (2 loads per half): rows srow, srow+64 of a 128-row half
    const int srow = w * 8 + (lane >> 3);
    const int scol = ((lane & 7) ^ (lane >> 3)) * 8;
    const ushort_t* gA = A + (m0 + srow) * (size_t)K + kbeg + scol;
    // B staging (1 load per 64-row half): row tid>>3, chunk pre-swizzled
    const int srB  = tid >> 3;
    const int scB  = ((tid & 7) ^ (srB & 7)) * 8;
    const ushort_t* gB = Bt + (n0 + srB) * (size_t)K + kbeg + scB;

    const int wm = w >> 1, wn = w & 1;
    const int aRow = (wm * 32 + qn) * 64;
    const int bRow = (wn * 32 + qn) * 64;
    const int sw0 = ((quad * 16)      ^ ((qn & 7) << 4)) >> 1;
    const int sw1 = ((64 + quad * 16) ^ ((qn & 7) << 4)) >> 1;

#define OSTG_A(t, h, buf)                                                      \
    do { if ((t) < NT) {                                                       \
        const ushort_t* g = gA + (size_t)(h) * 128 * K + (t) * 64;             \
        ushort_t* d = ldsp + (buf) * 24576 + (h) * 8192 + w * 512;             \
        gl_lds16(g, d);                                                        \
        gl_lds16(g + 64 * (size_t)K, d + 4096);                                \
    } } while (0)
#define OSTG_B(t, h, buf)                                                      \
    do { if ((t) < NT) {                                                       \
        const ushort_t* g = gB + (size_t)(h) * 64 * K + (t) * 64;              \
        ushort_t* d = ldsp + (buf) * 24576 + 16384 + (h) * 4096 + w * 512;     \
        gl_lds16(g, d);                                                        \
    } } while (0)

#define OPHASE(cb, p, qr, qc, STAGE, BOUND)                                    \
    do {                                                                       \
        const ushort_t* bA = ldsp + (cb) * 24576 + (qr) * 8192;                \
        const ushort_t* bB = ldsp + (cb) * 24576 + 16384 + (qc) * 4096;        \
        bf16x8 af[2][2], bv[2][2];                                             \
        _Pragma("unroll")                                                      \
        for (int mi = 0; mi < 2; mi++) {                                       \
            af[mi][0] = *(const bf16x8*)(bA + aRow + mi * 1024 + sw0);         \
            af[mi][1] = *(const bf16x8*)(bA + aRow + mi * 1024 + sw1);         \
        }                                                                      \
        _Pragma("unroll")                                                      \
        for (int nj = 0; nj < 2; nj++) {                                       \
            bv[nj][0] = *(const bf16x8*)(bB + bRow + nj * 1024 + sw0);         \
            bv[nj][1] = *(const bf16x8*)(bB + bRow + nj * 1024 + sw1);         \
        }                                                                      \
        asm volatile("" ::: "memory");                                         \
        STAGE;                                                                 \
        BOUND;                                                                 \
        __builtin_amdgcn_s_barrier();                                          \
        asm volatile("s_waitcnt lgkmcnt(0)" ::: "memory");                     \
        __builtin_amdgcn_sched_barrier(0);                                     \
        __builtin_amdgcn_s_setprio(1);                                         \
        _Pragma("unroll")                                                      \
        for (int mi = 0; mi < 2; mi++)                                         \
            _Pragma("unroll")                                                  \
            for (int nj = 0; nj < 2; nj++) {                                   \
                acc[p][mi][nj] = mfma16(af[mi][0], bv[nj][0], acc[p][mi][nj]); \
                acc[p][mi][nj] = mfma16(af[mi][1], bv[nj][1], acc[p][mi][nj]); \
            }                                                                  \
        __builtin_amdgcn_s_setprio(0);                                         \
        __builtin_amdgcn_s_barrier();                                          \
    } while (0)

    f32x4 acc[4][2][2];
    f32x4 zero = {0.f, 0.f, 0.f, 0.f};
    #pragma unroll
    for (int p = 0; p < 4; p++)
        #pragma unroll
        for (int mi = 0; mi < 2; mi++)
            #pragma unroll
            for (int nj = 0; nj < 2; nj++) acc[p][mi][nj] = zero;

    OSTG_A(0, 0, 0); OSTG_B(0, 0, 0); OSTG_B(0, 1, 0); OSTG_A(0, 1, 0);
    OSTG_A(1, 0, 1); OSTG_B(1, 0, 1);
    asm volatile("s_waitcnt vmcnt(0)" ::: "memory");
    __builtin_amdgcn_s_barrier();

    for (int t2 = 0; t2 < NT; t2 += 2) {
        OPHASE(0, 0, 0, 0, OSTG_B(t2 + 1, 1, 1), (void)0);
        OPHASE(0, 1, 0, 1, OSTG_A(t2 + 1, 1, 1), (void)0);
        OPHASE(0, 2, 1, 0, OSTG_A(t2 + 2, 0, 0), (void)0);
        OPHASE(0, 3, 1, 1, OSTG_B(t2 + 2, 0, 0),
               if (t2 == NT - 2) { asm volatile("s_waitcnt vmcnt(0)" ::: "memory"); }
               else              { asm volatile("s_waitcnt vmcnt(3)" ::: "memory"); });
        OPHASE(1, 0, 0, 0, OSTG_B(t2 + 2, 1, 0), (void)0);
        OPHASE(1, 1, 0, 1, OSTG_A(t2 + 2, 1, 0), (void)0);
        OPHASE(1, 2, 1, 0, OSTG_A(t2 + 3, 0, 1), (void)0);
        OPHASE(1, 3, 1, 1, OSTG_B(t2 + 3, 0, 1),
               asm volatile("s_waitcnt vmcnt(3)" ::: "memory"););
    }
#undef OPHASE
#undef OSTG_A
#undef OSTG_B

    #pragma unroll
    for (int p = 0; p < 4; p++) {
        const int qr = p >> 1, qc = p & 1;
        #pragma unroll
        for (int mi = 0; mi < 2; mi++)
            #pragma unroll
            for (int nj = 0; nj < 2; nj++) {
                const long row0 = m0 + qr * 128 + wm * 32 + mi * 16 + quad * 4;
                const long col  = n0 + qc * 64 + wn * 32 + nj * 16 + qn;
                #pragma unroll
                for (int r = 0; r < 4; r++)
                    Cout[(row0 + r) * N + col] = acc[p][mi][nj][r];
            }
    }
}

// ---------- fused combine + RoPE + V-transpose (R1 verbatim) ----------
__global__ __launch_bounds__(256) void fuse_crv(const ushort_t* __restrict__ p0,
                                                const ushort_t* __restrict__ p1,
                                                const float* __restrict__ cs,
                                                const float* __restrict__ sn,
                                                ushort_t* __restrict__ qd,
                                                ushort_t* __restrict__ kd,
                                                ushort_t* __restrict__ vt) {
    __shared__ ushort_t tl[64][65];
    const int cx = blockIdx.x;               // 0..47
    const int ty = blockIdx.y;               // 0..31
    const int r  = threadIdx.x >> 2;         // 0..63
    const int c0 = (threadIdx.x & 3) << 4;   // 0,16,32,48
    const int t  = ty * 64 + r;
    const size_t base = (size_t)t * 3072 + cx * 64;

    if (cx < 40) {                           // q or k: combine + rope
        const int cp = c0 ^ 32;
        float own[16], par[16];
        #pragma unroll
        for (int jj = 0; jj < 2; jj++) {
            uint4 a = *(const uint4*)(p0 + base + c0 + jj * 8);
            uint4 b = *(const uint4*)(p1 + base + c0 + jj * 8);
            uint4 c = *(const uint4*)(p0 + base + cp + jj * 8);
            uint4 d = *(const uint4*)(p1 + base + cp + jj * 8);
            const ushort_t* pa = (const ushort_t*)&a;
            const ushort_t* pb = (const ushort_t*)&b;
            const ushort_t* pc = (const ushort_t*)&c;
            const ushort_t* pd = (const ushort_t*)&d;
            #pragma unroll
            for (int e = 0; e < 8; e++) {
                own[jj * 8 + e] = b2f(pa[e]) + b2f(pb[e]);
                par[jj * 8 + e] = b2f(pc[e]) + b2f(pd[e]);
            }
        }
        float cs16[16], sn16[16];
        #pragma unroll
        for (int jj = 0; jj < 4; jj++) {
            float4 c4 = *(const float4*)(cs + (size_t)t * 64 + c0 + jj * 4);
            float4 s4 = *(const float4*)(sn + (size_t)t * 64 + c0 + jj * 4);
            cs16[jj * 4 + 0] = c4.x; cs16[jj * 4 + 1] = c4.y;
            cs16[jj * 4 + 2] = c4.z; cs16[jj * 4 + 3] = c4.w;
            sn16[jj * 4 + 0] = s4.x; sn16[jj * 4 + 1] = s4.y;
            sn16[jj * 4 + 2] = s4.z; sn16[jj * 4 + 3] = s4.w;
        }
        const float scale = (cx < 32) ? 0.18033688f : 1.0f;  // q: (1/8)*log2e
        union { ushort_t u[16]; uint4 v[2]; } o;
        #pragma unroll
        for (int j = 0; j < 16; j++) {
            const int d = c0 + j;
            const float pr = (d < 32) ? -par[j] : par[j];
            o.u[j] = f2b((own[j] * cs16[j] + pr * sn16[j]) * scale);
        }
        if (cx < 32) {
            ushort_t* dst = qd + (size_t)t * 2048 + cx * 64 + c0;
            *(uint4*)dst = o.v[0]; *(uint4*)(dst + 8) = o.v[1];
        } else {
            ushort_t* dst = kd + (size_t)t * 512 + (cx - 32) * 64 + c0;
            *(uint4*)dst = o.v[0]; *(uint4*)(dst + 8) = o.v[1];
        }
    } else {                                 // v: combine + transpose via LDS
        #pragma unroll
        for (int jj = 0; jj < 2; jj++) {
            uint4 a = *(const uint4*)(p0 + base + c0 + jj * 8);
            uint4 b = *(const uint4*)(p1 + base + c0 + jj * 8);
            const ushort_t* pa = (const ushort_t*)&a;
            const ushort_t* pb = (const ushort_t*)&b;
            #pragma unroll
            for (int e = 0; e < 8; e++)
                tl[r][c0 + jj * 8 + e] = f2b(b2f(pa[e]) + b2f(pb[e]));
        }
        __syncthreads();
        const int rr  = threadIdx.x >> 3;        // 0..31
        const int cc8 = (threadIdx.x & 7) * 8;
        const int db = (cx - 40) * 64, tb = ty * 64;
        #pragma unroll
        for (int h = 0; h < 2; h++) {
            const int d = rr + h * 32;
            ushort4 o0, o1;
            o0.x = tl[cc8 + 0][d]; o0.y = tl[cc8 + 1][d];
            o0.z = tl[cc8 + 2][d]; o0.w = tl[cc8 + 3][d];
            o1.x = tl[cc8 + 4][d]; o1.y = tl[cc8 + 5][d];
            o1.z = tl[cc8 + 6][d]; o1.w = tl[cc8 + 7][d];
            *(ushort4*)(vt + (size_t)(db + d) * 2048 + tb + cc8)     = o0;
            *(ushort4*)(vt + (size_t)(db + d) * 2048 + tb + cc8 + 4) = o1;
        }
    }
}

// ---------- combine O partials -> fp32 out ----------
__global__ __launch_bounds__(256) void combine_o(const float4* __restrict__ s0,
                                                 const float4* __restrict__ s1,
                                                 float4* __restrict__ out) {
    for (int i = blockIdx.x * 256 + threadIdx.x; i < 1048576; i += 2048 * 256) {
        float4 a = s0[i], b = s1[i];
        float4 r; r.x = a.x + b.x; r.y = a.y + b.y; r.z = a.z + b.z; r.w = a.w + b.w;
        out[i] = r;
    }
}

// ---------- flash attention, causal, GQA G=4 ----------
// R12: P-scratch stride 80 -> 68 shorts. Bank math: quad advances 4 rows =
// 4*68 shorts = 136 words; 136 mod 32 = 8 -> quads at bank offsets {0,8,16,24}
// -> the 16 per-tile P-writes are conflict-free (stride 80 had 4*80/2=160 ≡ 0
// mod 32: all quads stacked -> 4-way, the measured 2.16M conflicts). Reads
// (qn*34+quad*4 words) are <=4-way x 2 instrs. Plus native f2b (1 VALU op).
__global__ __launch_bounds__(256) void attn_kernel(const ushort_t* __restrict__ Q,
                                                   const ushort_t* __restrict__ Kb,
                                                   const ushort_t* __restrict__ Vt,
                                                   ushort_t* __restrict__ Ob) {
    __shared__ ushort_t Ks[2 * 4096];     // 16 KB
    __shared__ ushort_t Vs[2 * 4096];     // 16 KB
    __shared__ ushort_t pl[4 * 16 * 68];  // 8.5 KB: per-wave P, 16 rows (stride 68)
    const int tid  = threadIdx.x;
    const int lane = tid & 63, wid = tid >> 6;
    const int qn = lane & 15, quad = lane >> 4;
    const int h   = blockIdx.x & 31;
    const int qb  = 31 - (blockIdx.x >> 5);     // heavy first, 0..31 (64-row blocks)
    const int kvb = (h >> 2) * 64;
    const int trow = qb * 64 + wid * 16;
    ushort_t* plw = pl + wid * 16 * 68;
    f32x4 zero = {0.f, 0.f, 0.f, 0.f};

    const ushort_t* qpA = Q + (size_t)(trow + qn) * 2048 + h * 64 + quad * 8;
    const bf16x8 qA0 = ld8(qpA), qA1 = ld8(qpA + 32);

    f32x4 oA[4] = {zero, zero, zero, zero};
    float lA[4] = {0.f, 0.f, 0.f, 0.f};
    const int ntiles = qb + 1;

#define STAGE(s0, buf)                                                         \
    do {                                                                       \
        const ushort_t* kg = Kb + (size_t)((s0) + lane) * 512 + kvb + wid * 8; \
        gl_lds16(kg,      Ks + (buf) * 4096 + wid * 512);                      \
        gl_lds16(kg + 32, Ks + (buf) * 4096 + (wid + 4) * 512);                \
        const ushort_t* vg = Vt + (size_t)(kvb + lane) * 2048 + (s0) + wid * 8;\
        gl_lds16(vg,      Vs + (buf) * 4096 + wid * 512);                      \
        gl_lds16(vg + 32, Vs + (buf) * 4096 + (wid + 4) * 512);                \
    } while (0)

#define COMPUTE(s0, buf)                                                       \
    do {                                                                       \
        f32x4 scA[4];                                                          \
        __builtin_amdgcn_s_setprio(1);                                         \
        _Pragma("unroll")                                                      \
        for (int cb = 0; cb < 4; cb++) {                                       \
            const bf16x8 kf0 = *(const bf16x8*)(Ks + (buf) * 4096 + quad * 512 + (cb * 16 + qn) * 8);       \
            const bf16x8 kf1 = *(const bf16x8*)(Ks + (buf) * 4096 + (quad + 4) * 512 + (cb * 16 + qn) * 8); \
            f32x4 s = mfma16(qA0, kf0, zero); scA[cb] = mfma16(qA1, kf1, s);   \
        }                                                                      \
        __builtin_amdgcn_s_setprio(0);                                         \
        const bool needmask = ((s0) + 63 > trow);                              \
        _Pragma("unroll")                                                      \
        for (int i = 0; i < 4; i++) {                                          \
            const int tA = trow + quad * 4 + i;                                \
            _Pragma("unroll")                                                  \
            for (int cb = 0; cb < 4; cb++) {                                   \
                const int col = (s0) + cb * 16 + qn;                           \
                float vA = scA[cb][i];                                         \
                if (needmask) {                                                \
                    if (col > tA) vA = -INFINITY;                              \
                }                                                              \
                const float pA = fexp2(vA);                                    \
                lA[i] += pA;                                                   \
                plw[(quad * 4 + i) * 68 + cb * 16 + qn] = f2b(pA);             \
            }                                                                  \
        }                                                                      \
        const bf16x8 pfA0 = *(const bf16x8*)(plw + qn * 68 + quad * 8);        \
        const bf16x8 pfA1 = *(const bf16x8*)(plw + qn * 68 + 32 + quad * 8);   \
        __builtin_amdgcn_s_setprio(1);                                         \
        _Pragma("unroll")                                                      \
        for (int dcb = 0; dcb < 4; dcb++) {                                    \
            const bf16x8 vf0 = *(const bf16x8*)(Vs + (buf) * 4096 + quad * 512 + (dcb * 16 + qn) * 8);       \
            const bf16x8 vf1 = *(const bf16x8*)(Vs + (buf) * 4096 + (quad + 4) * 512 + (dcb * 16 + qn) * 8); \
            oA[dcb] = mfma16(pfA0, vf0, oA[dcb]);                              \
            oA[dcb] = mfma16(pfA1, vf1, oA[dcb]);                              \
        }                                                                      \
        __builtin_amdgcn_s_setprio(0);                                         \
    } while (0)

    STAGE(0, 0);
    int t = 0;
    for (; t + 2 <= ntiles; t += 2) {
        __syncthreads();
        STAGE((t + 1) * 64, 1);
        COMPUTE(t * 64, 0);
        __syncthreads();
        if (t + 2 < ntiles) STAGE((t + 2) * 64, 0);
        COMPUTE((t + 1) * 64, 1);
    }
    if (t < ntiles) {                      // odd tail: buf0 already staged
        __syncthreads();
        COMPUTE(t * 64, 0);
    }
#undef STAGE
#undef COMPUTE

    #pragma unroll
    for (int i = 0; i < 4; i++) {
        float sA = lA[i];
        #pragma unroll
        for (int off = 1; off < 16; off <<= 1)
            sA += __shfl_xor(sA, off, 64);
        const float invA = 1.0f / sA;
        ushort_t* obA = Ob + (size_t)(trow + quad * 4 + i) * 2048 + h * 64 + qn;
        obA[0]  = f2b(oA[0][i] * invA);
        obA[16] = f2b(oA[1][i] * invA);
        obA[32] = f2b(oA[2][i] * invA);
        obA[48] = f2b(oA[3][i] * invA);
    }
}

// ---------- launch ----------
extern "C" void kernel_launch(void* const* d_in, const int* in_sizes, int n_in,
                              void* d_out, int out_size, void* d_ws, size_t ws_size,
                              hipStream_t stream) {
    const float* x    = (const float*)d_in[0];
    const float* cosp = (const float*)d_in[1];
    const float* sinp = (const float*)d_in[2];
    // d_in[3] = attention_mask_4d (pure causal; recomputed in-kernel)
    const float* Wq = (const float*)d_in[4];
    const float* Wk = (const float*)d_in[5];
    const float* Wv = (const float*)d_in[6];
    const float* Wo = (const float*)d_in[7];
    char* ws = (char*)d_ws;
    (void)ws_size; (void)in_sizes; (void)n_in; (void)out_size;

    ushort_t* xb    = (ushort_t*)(ws + WS_XB);
    ushort_t* wqkvb = (ushort_t*)(ws + WS_WQKV);
    ushort_t* wob   = (ushort_t*)(ws + WS_WO);
    ushort_t* p0    = (ushort_t*)(ws + WS_P0);
    ushort_t* p1    = (ushort_t*)(ws + WS_P1);
    ushort_t* qbb   = (ushort_t*)(ws + WS_QBB);
    ushort_t* kbb   = (ushort_t*)(ws + WS_KBB);
    ushort_t* vtg   = (ushort_t*)(ws + WS_VTG);
    ushort_t* ab    = (ushort_t*)(ws + WS_AB);
    float*    o0    = (float*)   (ws + WS_O0);
    float*    o1    = (float*)   (ws + WS_O1);

    // 1. convert inputs/weights to bf16 (contiguous dst: xb|wqkvb|wob)
    cvt_all<<<14336, 256, 0, stream>>>(x, Wq, Wk, Wv, Wo, xb);

    // 2. QKV projection split-K=2: 256^2 8-phase, 192 blocks (proven R8)
    gemm256<1><<<dim3(12, 8, 2), 512, 0, stream>>>(xb, wqkvb, p0, p1, 3072, 2048);

    // 3. fused combine + RoPE(q scale=(1/8)*log2e) + V transpose
    fuse_crv<<<dim3(48, 32), 256, 0, stream>>>(p0, p1, cosp, sinp, qbb, kbb, vtg);

    // 4. attention: 1024 blocks, 64 q-rows each
    attn_kernel<<<1024, 256, 0, stream>>>(qbb, kbb, vtg, ab);

    // 5. O-projection split-K=2: 256x128 8-phase, 256 blocks = 1/CU (full chip)
    gemm_op<<<dim3(16, 8, 2), 512, 0, stream>>>(ab, wob, o0, o1, 2048, 2048);

    // 6. combine partials into fp32 output
    combine_o<<<2048, 256, 0, stream>>>((const float4*)o0, (const float4*)o1,
                                        (float4*)d_out);
}

// Round 10
// 250.833 us; speedup vs baseline: 1.2336x; 1.0152x over previous
//
#include <hip/hip_runtime.h>
#include <math.h>

// ---------- types ----------
typedef __attribute__((ext_vector_type(8))) __bf16 bf16x8;
typedef __attribute__((ext_vector_type(4))) float  f32x4;
typedef unsigned short ushort_t;
typedef unsigned int   uint_t;

static __device__ inline f32x4 mfma16(bf16x8 a, bf16x8 b, f32x4 c) {
    return __builtin_amdgcn_mfma_f32_16x16x32_bf16(a, b, c, 0, 0, 0);
}

// R13: reverted to the R8-proven RNE bit-trick (no NaN-quieting branch; finite
// inputs only). The native (__bf16) cast was one of two confounded R9 changes.
static __device__ inline ushort_t f2b(float f) {
    uint_t u = __builtin_bit_cast(uint_t, f);
    u = (u + 0x7FFFu + ((u >> 16) & 1u)) >> 16;
    return (ushort_t)u;
}
static __device__ inline float b2f(ushort_t u) {
    uint_t x = ((uint_t)u) << 16;
    return __builtin_bit_cast(float, x);
}
static __device__ inline bf16x8 ld8(const ushort_t* p) {
    uint4 v = *(const uint4*)p;
    return __builtin_bit_cast(bf16x8, v);
}
static __device__ inline float fexp2(float x) {
#if __has_builtin(__builtin_amdgcn_exp2f)
    return __builtin_amdgcn_exp2f(x);
#else
    return exp2f(x);
#endif
}

// async global->LDS, 16B per lane; LDS dst = base + lane*16 (wave-uniform base!)
static __device__ inline void gl_lds16(const ushort_t* g, ushort_t* l) {
    __builtin_amdgcn_global_load_lds(
        (const __attribute__((address_space(1))) void*)(g),
        (__attribute__((address_space(3))) void*)(l),
        16, 0, 0);
}

// ---------- ws layout (peak = 62,914,560 B, R1 layout) ----------
#define WS_XB     0          //  8 MiB x bf16           [2048,2048]   (dead after QKV gemm)
#define WS_WQKV   8388608    // 12 MiB [Wq;Wk;Wv] bf16  [3072,2048]   (dead after QKV gemm)
#define WS_WO     20971520   //  8 MiB Wo bf16          [2048,2048]
#define WS_P0     29360128   // 12 MiB QKV partial 0 bf16 [2048,3072] (dead after fuse)
#define WS_P1     41943040   // 12 MiB QKV partial 1 bf16 [2048,3072] (dead after fuse)
#define WS_QBB    0          //  8 MiB q roped bf16     (overlays xb)
#define WS_KBB    8388608    //  2 MiB k roped bf16     (overlays wqkvb head)
#define WS_VTG    10485760   //  2 MiB V^T bf16 [512,2048]
#define WS_AB     12582912   //  8 MiB attn out bf16    (ends exactly at WS_WO)
#define WS_O0     29360128   // 16 MiB O partial 0 fp32 (overlays p0)
#define WS_O1     46137344   // 16 MiB O partial 1 fp32 (ends 62914560)

// ---------- fp32 -> bf16 convert for x|Wq|Wk|Wv|Wo (contiguous dst) ----------
__global__ __launch_bounds__(256) void cvt_all(const float* __restrict__ x,
                                               const float* __restrict__ wq,
                                               const float* __restrict__ wk,
                                               const float* __restrict__ wv,
                                               const float* __restrict__ wo,
                                               ushort_t* __restrict__ dst) {
    const size_t i = (size_t)(blockIdx.x * 256 + threadIdx.x) * 4;
    const float* src; size_t off;
    if (i < 4194304)       { src = x;  off = 0; }
    else if (i < 8388608)  { src = wq; off = 4194304; }
    else if (i < 9437184)  { src = wk; off = 8388608; }
    else if (i < 10485760) { src = wv; off = 9437184; }
    else                   { src = wo; off = 10485760; }
    float4 v = *(const float4*)(src + (i - off));
    ushort4 o;
    o.x = f2b(v.x); o.y = f2b(v.y); o.z = f2b(v.z); o.w = f2b(v.w);
    *(ushort4*)(dst + i) = o;
}

// ---------- 256x256 8-phase GEMM (proven R8; QKV only) ----------
// 8 waves, BK=64, LDS 128 KiB = 2 buf x {A 32K | B 32K}, each as two 128x64
// halves. Phase p of a tile computes C-quadrant (p>>1,p&1); wave (w>>2,w&3)
// owns 64x32. Half-use: A0 p0,p1 / B0 p0,p2 / B1 p1,p3 / A1 p2,p3. Stage
// stream: p0:B1(t+1) p1:A1(t+1) p2:A0(t+2) p3:B0(t+2). Boundary vmcnt(4);
// vmcnt(0) only entering the final tile. T2 swizzle via pre-swizzled global
// source + XOR'd reads.
template <int OUTB>
__global__ __launch_bounds__(512, 2) void gemm256(const ushort_t* __restrict__ A,
                                                  const ushort_t* __restrict__ Bt,
                                                  void* __restrict__ C0,
                                                  void* __restrict__ C1,
                                                  int N, int K) {
    __shared__ ushort_t lds[65536];   // 128 KiB
    const int tid  = threadIdx.x;
    const int lane = tid & 63, w = tid >> 6;
    const int qn = lane & 15, quad = lane >> 4;
    const long m0 = (long)blockIdx.y * 256;
    const long n0 = (long)blockIdx.x * 256;
    const int kh   = K >> 1;
    const int kbeg = blockIdx.z * kh;
    const int NT   = kh >> 6;                  // even, >=4
    void* Cout = blockIdx.z ? C1 : C0;
    ushort_t* ldsp = lds;

    const int srow = w * 8 + (lane >> 3);
    const int scol = ((lane & 7) ^ (lane >> 3)) * 8;
    const ushort_t* gA = A  + (m0 + srow) * (size_t)K + kbeg + scol;
    const ushort_t* gB = Bt + (n0 + srow) * (size_t)K + kbeg + scol;

    const int aRow = ((w >> 2) * 64 + qn) * 64;
    const int bRow = ((w & 3) * 32 + qn) * 64;
    const int sw0 = ((quad * 16)      ^ ((qn & 7) << 4)) >> 1;   // ks=0
    const int sw1 = ((64 + quad * 16) ^ ((qn & 7) << 4)) >> 1;   // ks=1

#define STG_A(t, h, buf)                                                       \
    do { if ((t) < NT) {                                                       \
        const ushort_t* g = gA + (size_t)(h) * 128 * K + (t) * 64;             \
        ushort_t* d = ldsp + (buf) * 32768 + (h) * 8192 + w * 512;             \
        gl_lds16(g, d);                                                        \
        gl_lds16(g + 64 * (size_t)K, d + 4096);                                \
    } } while (0)
#define STG_B(t, h, buf)                                                       \
    do { if ((t) < NT) {                                                       \
        const ushort_t* g = gB + (size_t)(h) * 128 * K + (t) * 64;             \
        ushort_t* d = ldsp + (buf) * 32768 + 16384 + (h) * 8192 + w * 512;     \
        gl_lds16(g, d);                                                        \
        gl_lds16(g + 64 * (size_t)K, d + 4096);                                \
    } } while (0)

#define PHASE(cb, p, qr, qc, STAGE, BOUND)                                     \
    do {                                                                       \
        const ushort_t* bA = ldsp + (cb) * 32768 + (qr) * 8192;                \
        const ushort_t* bB = ldsp + (cb) * 32768 + 16384 + (qc) * 8192;        \
        bf16x8 af[4][2], bv[2][2];                                             \
        _Pragma("unroll")                                                      \
        for (int mi = 0; mi < 4; mi++) {                                       \
            af[mi][0] = *(const bf16x8*)(bA + aRow + mi * 1024 + sw0);         \
            af[mi][1] = *(const bf16x8*)(bA + aRow + mi * 1024 + sw1);         \
        }                                                                      \
        _Pragma("unroll")                                                      \
        for (int nj = 0; nj < 2; nj++) {                                       \
            bv[nj][0] = *(const bf16x8*)(bB + bRow + nj * 1024 + sw0);         \
            bv[nj][1] = *(const bf16x8*)(bB + bRow + nj * 1024 + sw1);         \
        }                                                                      \
        asm volatile("" ::: "memory");  /* pin reads above the stage */        \
        STAGE;                                                                 \
        BOUND;                                                                 \
        __builtin_amdgcn_s_barrier();                                          \
        asm volatile("s_waitcnt lgkmcnt(0)" ::: "memory");                     \
        __builtin_amdgcn_sched_barrier(0);                                     \
        __builtin_amdgcn_s_setprio(1);                                         \
        _Pragma("unroll")                                                      \
        for (int mi = 0; mi < 4; mi++)                                         \
            _Pragma("unroll")                                                  \
            for (int nj = 0; nj < 2; nj++) {                                   \
                acc[p][mi][nj] = mfma16(af[mi][0], bv[nj][0], acc[p][mi][nj]); \
                acc[p][mi][nj] = mfma16(af[mi][1], bv[nj][1], acc[p][mi][nj]); \
            }                                                                  \
        __builtin_amdgcn_s_setprio(0);                                         \
        __builtin_amdgcn_s_barrier();                                          \
    } while (0)

    f32x4 acc[4][4][2];
    f32x4 zero = {0.f, 0.f, 0.f, 0.f};
    #pragma unroll
    for (int p = 0; p < 4; p++)
        #pragma unroll
        for (int mi = 0; mi < 4; mi++)
            #pragma unroll
            for (int nj = 0; nj < 2; nj++) acc[p][mi][nj] = zero;

    STG_A(0, 0, 0); STG_B(0, 0, 0); STG_B(0, 1, 0); STG_A(0, 1, 0);
    STG_A(1, 0, 1); STG_B(1, 0, 1);
    asm volatile("s_waitcnt vmcnt(0)" ::: "memory");
    __builtin_amdgcn_s_barrier();

    for (int t2 = 0; t2 < NT; t2 += 2) {
        PHASE(0, 0, 0, 0, STG_B(t2 + 1, 1, 1), (void)0);
        PHASE(0, 1, 0, 1, STG_A(t2 + 1, 1, 1), (void)0);
        PHASE(0, 2, 1, 0, STG_A(t2 + 2, 0, 0), (void)0);
        PHASE(0, 3, 1, 1, STG_B(t2 + 2, 0, 0),
              if (t2 == NT - 2) { asm volatile("s_waitcnt vmcnt(0)" ::: "memory"); }
              else              { asm volatile("s_waitcnt vmcnt(4)" ::: "memory"); });
        PHASE(1, 0, 0, 0, STG_B(t2 + 2, 1, 0), (void)0);
        PHASE(1, 1, 0, 1, STG_A(t2 + 2, 1, 0), (void)0);
        PHASE(1, 2, 1, 0, STG_A(t2 + 3, 0, 1), (void)0);
        PHASE(1, 3, 1, 1, STG_B(t2 + 3, 0, 1),
              asm volatile("s_waitcnt vmcnt(4)" ::: "memory"););
    }
#undef PHASE
#undef STG_A
#undef STG_B

    #pragma unroll
    for (int p = 0; p < 4; p++) {
        const int qr = p >> 1, qc = p & 1;
        #pragma unroll
        for (int mi = 0; mi < 4; mi++)
            #pragma unroll
            for (int nj = 0; nj < 2; nj++) {
                const long row0 = m0 + qr * 128 + (w >> 2) * 64 + mi * 16 + quad * 4;
                const long col  = n0 + qc * 128 + (w & 3) * 32 + nj * 16 + qn;
                #pragma unroll
                for (int r = 0; r < 4; r++) {
                    if (OUTB)
                        ((ushort_t*)Cout)[(row0 + r) * N + col] = f2b(acc[p][mi][nj][r]);
                    else
                        ((float*)Cout)[(row0 + r) * N + col] = acc[p][mi][nj][r];
                }
            }
    }
}

// ---------- 256x128 8-phase GEMM (O-projection; proven R9) ----------
// BN=128 so the grid reaches 256 blocks = 1/CU. LDS 96 KiB; B-halves 64 cols
// (1 gl_lds). Phases (A0,B0)(A0,B1)(A1,B0)(A1,B1); wave (w>>1,w&1) owns 32x32.
// Stage stream p0:B1(t+1) p1:A1(t+1) p2:A0(t+2) p3:B0(t+2); boundary vmcnt(3);
// vmcnt(0) entering the final tile.
__global__ __launch_bounds__(512, 2) void gemm_op(const ushort_t* __restrict__ A,
                                                  const ushort_t* __restrict__ Bt,
                                                  float* __restrict__ C0,
                                                  float* __restrict__ C1,
                                                  int N, int K) {
    __shared__ ushort_t lds[49152];   // 96 KiB
    const int tid  = threadIdx.x;
    const int lane = tid & 63, w = tid >> 6;
    const int qn = lane & 15, quad = lane >> 4;
    const long m0 = (long)blockIdx.y * 256;
    const long n0 = (long)blockIdx.x * 128;
    const int kh   = K >> 1;
    const int kbeg = blockIdx.z * kh;
    const int NT   = kh >> 6;                  // even, >=4 (16 here)
    float* Cout = blockIdx.z ? C1 : C0;
    ushort_t* ldsp = lds;

    const int srow = w * 8 + (lane >> 3);
    const int scol = ((lane & 7) ^ (lane >> 3)) * 8;
    const ushort_t* gA = A + (m0 + srow) * (size_t)K + kbeg + scol;
    const int srB  = tid >> 3;
    const int scB  = ((tid & 7) ^ (srB & 7)) * 8;
    const ushort_t* gB = Bt + (n0 + srB) * (size_t)K + kbeg + scB;

    const int wm = w >> 1, wn = w & 1;
    const int aRow = (wm * 32 + qn) * 64;
    const int bRow = (wn * 32 + qn) * 64;
    const int sw0 = ((quad * 16)      ^ ((qn & 7) << 4)) >> 1;
    const int sw1 = ((64 + quad * 16) ^ ((qn & 7) << 4)) >> 1;

#define OSTG_A(t, h, buf)                                                      \
    do { if ((t) < NT) {                                                       \
        const ushort_t* g = gA + (size_t)(h) * 128 * K + (t) * 64;             \
        ushort_t* d = ldsp + (buf) * 24576 + (h) * 8192 + w * 512;             \
        gl_lds16(g, d);                                                        \
        gl_lds16(g + 64 * (size_t)K, d + 4096);                                \
    } } while (0)
#define OSTG_B(t, h, buf)                                                      \
    do { if ((t) < NT) {                                                       \
        const ushort_t* g = gB + (size_t)(h) * 64 * K + (t) * 64;              \
        ushort_t* d = ldsp + (buf) * 24576 + 16384 + (h) * 4096 + w * 512;     \
        gl_lds16(g, d);                                                        \
    } } while (0)

#define OPHASE(cb, p, qr, qc, STAGE, BOUND)                                    \
    do {                                                                       \
        const ushort_t* bA = ldsp + (cb) * 24576 + (qr) * 8192;                \
        const ushort_t* bB = ldsp + (cb) * 24576 + 16384 + (qc) * 4096;        \
        bf16x8 af[2][2], bv[2][2];                                             \
        _Pragma("unroll")                                                      \
        for (int mi = 0; mi < 2; mi++) {                                       \
            af[mi][0] = *(const bf16x8*)(bA + aRow + mi * 1024 + sw0);         \
            af[mi][1] = *(const bf16x8*)(bA + aRow + mi * 1024 + sw1);         \
        }                                                                      \
        _Pragma("unroll")                                                      \
        for (int nj = 0; nj < 2; nj++) {                                       \
            bv[nj][0] = *(const bf16x8*)(bB + bRow + nj * 1024 + sw0);         \
            bv[nj][1] = *(const bf16x8*)(bB + bRow + nj * 1024 + sw1);         \
        }                                                                      \
        asm volatile("" ::: "memory");                                         \
        STAGE;                                                                 \
        BOUND;                                                                 \
        __builtin_amdgcn_s_barrier();                                          \
        asm volatile("s_waitcnt lgkmcnt(0)" ::: "memory");                     \
        __builtin_amdgcn_sched_barrier(0);                                     \
        __builtin_amdgcn_s_setprio(1);                                         \
        _Pragma("unroll")                                                      \
        for (int mi = 0; mi < 2; mi++)                                         \
            _Pragma("unroll")                                                  \
            for (int nj = 0; nj < 2; nj++) {                                   \
                acc[p][mi][nj] = mfma16(af[mi][0], bv[nj][0], acc[p][mi][nj]); \
                acc[p][mi][nj] = mfma16(af[mi][1], bv[nj][1], acc[p][mi][nj]); \
            }                                                                  \
        __builtin_amdgcn_s_setprio(0);                                         \
        __builtin_amdgcn_s_barrier();                                          \
    } while (0)

    f32x4 acc[4][2][2];
    f32x4 zero = {0.f, 0.f, 0.f, 0.f};
    #pragma unroll
    for (int p = 0; p < 4; p++)
        #pragma unroll
        for (int mi = 0; mi < 2; mi++)
            #pragma unroll
            for (int nj = 0; nj < 2; nj++) acc[p][mi][nj] = zero;

    OSTG_A(0, 0, 0); OSTG_B(0, 0, 0); OSTG_B(0, 1, 0); OSTG_A(0, 1, 0);
    OSTG_A(1, 0, 1); OSTG_B(1, 0, 1);
    asm volatile("s_waitcnt vmcnt(0)" ::: "memory");
    __builtin_amdgcn_s_barrier();

    for (int t2 = 0; t2 < NT; t2 += 2) {
        OPHASE(0, 0, 0, 0, OSTG_B(t2 + 1, 1, 1), (void)0);
        OPHASE(0, 1, 0, 1, OSTG_A(t2 + 1, 1, 1), (void)0);
        OPHASE(0, 2, 1, 0, OSTG_A(t2 + 2, 0, 0), (void)0);
        OPHASE(0, 3, 1, 1, OSTG_B(t2 + 2, 0, 0),
               if (t2 == NT - 2) { asm volatile("s_waitcnt vmcnt(0)" ::: "memory"); }
               else              { asm volatile("s_waitcnt vmcnt(3)" ::: "memory"); });
        OPHASE(1, 0, 0, 0, OSTG_B(t2 + 2, 1, 0), (void)0);
        OPHASE(1, 1, 0, 1, OSTG_A(t2 + 2, 1, 0), (void)0);
        OPHASE(1, 2, 1, 0, OSTG_A(t2 + 3, 0, 1), (void)0);
        OPHASE(1, 3, 1, 1, OSTG_B(t2 + 3, 0, 1),
               asm volatile("s_waitcnt vmcnt(3)" ::: "memory"););
    }
#undef OPHASE
#undef OSTG_A
#undef OSTG_B

    #pragma unroll
    for (int p = 0; p < 4; p++) {
        const int qr = p >> 1, qc = p & 1;
        #pragma unroll
        for (int mi = 0; mi < 2; mi++)
            #pragma unroll
            for (int nj = 0; nj < 2; nj++) {
                const long row0 = m0 + qr * 128 + wm * 32 + mi * 16 + quad * 4;
                const long col  = n0 + qc * 64 + wn * 32 + nj * 16 + qn;
                #pragma unroll
                for (int r = 0; r < 4; r++)
                    Cout[(row0 + r) * N + col] = acc[p][mi][nj][r];
            }
    }
}

// ---------- fused combine + RoPE + V-transpose (R1 verbatim) ----------
__global__ __launch_bounds__(256) void fuse_crv(const ushort_t* __restrict__ p0,
                                                const ushort_t* __restrict__ p1,
                                                const float* __restrict__ cs,
                                                const float* __restrict__ sn,
                                                ushort_t* __restrict__ qd,
                                                ushort_t* __restrict__ kd,
                                                ushort_t* __restrict__ vt) {
    __shared__ ushort_t tl[64][65];
    const int cx = blockIdx.x;               // 0..47
    const int ty = blockIdx.y;               // 0..31
    const int r  = threadIdx.x >> 2;         // 0..63
    const int c0 = (threadIdx.x & 3) << 4;   // 0,16,32,48
    const int t  = ty * 64 + r;
    const size_t base = (size_t)t * 3072 + cx * 64;

    if (cx < 40) {                           // q or k: combine + rope
        const int cp = c0 ^ 32;
        float own[16], par[16];
        #pragma unroll
        for (int jj = 0; jj < 2; jj++) {
            uint4 a = *(const uint4*)(p0 + base + c0 + jj * 8);
            uint4 b = *(const uint4*)(p1 + base + c0 + jj * 8);
            uint4 c = *(const uint4*)(p0 + base + cp + jj * 8);
            uint4 d = *(const uint4*)(p1 + base + cp + jj * 8);
            const ushort_t* pa = (const ushort_t*)&a;
            const ushort_t* pb = (const ushort_t*)&b;
            const ushort_t* pc = (const ushort_t*)&c;
            const ushort_t* pd = (const ushort_t*)&d;
            #pragma unroll
            for (int e = 0; e < 8; e++) {
                own[jj * 8 + e] = b2f(pa[e]) + b2f(pb[e]);
                par[jj * 8 + e] = b2f(pc[e]) + b2f(pd[e]);
            }
        }
        float cs16[16], sn16[16];
        #pragma unroll
        for (int jj = 0; jj < 4; jj++) {
            float4 c4 = *(const float4*)(cs + (size_t)t * 64 + c0 + jj * 4);
            float4 s4 = *(const float4*)(sn + (size_t)t * 64 + c0 + jj * 4);
            cs16[jj * 4 + 0] = c4.x; cs16[jj * 4 + 1] = c4.y;
            cs16[jj * 4 + 2] = c4.z; cs16[jj * 4 + 3] = c4.w;
            sn16[jj * 4 + 0] = s4.x; sn16[jj * 4 + 1] = s4.y;
            sn16[jj * 4 + 2] = s4.z; sn16[jj * 4 + 3] = s4.w;
        }
        const float scale = (cx < 32) ? 0.18033688f : 1.0f;  // q: (1/8)*log2e
        union { ushort_t u[16]; uint4 v[2]; } o;
        #pragma unroll
        for (int j = 0; j < 16; j++) {
            const int d = c0 + j;
            const float pr = (d < 32) ? -par[j] : par[j];
            o.u[j] = f2b((own[j] * cs16[j] + pr * sn16[j]) * scale);
        }
        if (cx < 32) {
            ushort_t* dst = qd + (size_t)t * 2048 + cx * 64 + c0;
            *(uint4*)dst = o.v[0]; *(uint4*)(dst + 8) = o.v[1];
        } else {
            ushort_t* dst = kd + (size_t)t * 512 + (cx - 32) * 64 + c0;
            *(uint4*)dst = o.v[0]; *(uint4*)(dst + 8) = o.v[1];
        }
    } else {                                 // v: combine + transpose via LDS
        #pragma unroll
        for (int jj = 0; jj < 2; jj++) {
            uint4 a = *(const uint4*)(p0 + base + c0 + jj * 8);
            uint4 b = *(const uint4*)(p1 + base + c0 + jj * 8);
            const ushort_t* pa = (const ushort_t*)&a;
            const ushort_t* pb = (const ushort_t*)&b;
            #pragma unroll
            for (int e = 0; e < 8; e++)
                tl[r][c0 + jj * 8 + e] = f2b(b2f(pa[e]) + b2f(pb[e]));
        }
        __syncthreads();
        const int rr  = threadIdx.x >> 3;        // 0..31
        const int cc8 = (threadIdx.x & 7) * 8;
        const int db = (cx - 40) * 64, tb = ty * 64;
        #pragma unroll
        for (int h = 0; h < 2; h++) {
            const int d = rr + h * 32;
            ushort4 o0, o1;
            o0.x = tl[cc8 + 0][d]; o0.y = tl[cc8 + 1][d];
            o0.z = tl[cc8 + 2][d]; o0.w = tl[cc8 + 3][d];
            o1.x = tl[cc8 + 4][d]; o1.y = tl[cc8 + 5][d];
            o1.z = tl[cc8 + 6][d]; o1.w = tl[cc8 + 7][d];
            *(ushort4*)(vt + (size_t)(db + d) * 2048 + tb + cc8)     = o0;
            *(ushort4*)(vt + (size_t)(db + d) * 2048 + tb + cc8 + 4) = o1;
        }
    }
}

// ---------- combine O partials -> fp32 out ----------
__global__ __launch_bounds__(256) void combine_o(const float4* __restrict__ s0,
                                                 const float4* __restrict__ s1,
                                                 float4* __restrict__ out) {
    for (int i = blockIdx.x * 256 + threadIdx.x; i < 1048576; i += 2048 * 256) {
        float4 a = s0[i], b = s1[i];
        float4 r; r.x = a.x + b.x; r.y = a.y + b.y; r.z = a.z + b.z; r.w = a.w + b.w;
        out[i] = r;
    }
}

// ---------- flash attention, causal, GQA G=4 ----------
// R13: P-scratch stride 72 shorts (144 B/row).
//   * rows 16B-aligned -> pfA0/pfA1 are true ds_read_b128 (stride 68 broke
//     this: 136B rows put odd-qn reads at 8 mod 16 -> split/misaligned reads,
//     the uncounted stall behind R9's 55.4->62.9 regression);
//   * writes: quad advance = 4*72/2 = 144 words ≡ 16 mod 32 -> quads {0,16,0,16}
//     = 2-way (free, m136); stride 80's 4-way was the R8 2.16M counter;
//   * reads: row advance 36 words ≡ 4 mod 32 -> qn and qn+8 collide = 2-way (free).
// f2b reverted to R8-proven bit-trick.
__global__ __launch_bounds__(256) void attn_kernel(const ushort_t* __restrict__ Q,
                                                   const ushort_t* __restrict__ Kb,
                                                   const ushort_t* __restrict__ Vt,
                                                   ushort_t* __restrict__ Ob) {
    __shared__ ushort_t Ks[2 * 4096];     // 16 KB
    __shared__ ushort_t Vs[2 * 4096];     // 16 KB
    __shared__ ushort_t pl[4 * 16 * 72];  // 9 KB: per-wave P, 16 rows (stride 72)
    const int tid  = threadIdx.x;
    const int lane = tid & 63, wid = tid >> 6;
    const int qn = lane & 15, quad = lane >> 4;
    const int h   = blockIdx.x & 31;
    const int qb  = 31 - (blockIdx.x >> 5);     // heavy first, 0..31 (64-row blocks)
    const int kvb = (h >> 2) * 64;
    const int trow = qb * 64 + wid * 16;
    ushort_t* plw = pl + wid * 16 * 72;
    f32x4 zero = {0.f, 0.f, 0.f, 0.f};

    const ushort_t* qpA = Q + (size_t)(trow + qn) * 2048 + h * 64 + quad * 8;
    const bf16x8 qA0 = ld8(qpA), qA1 = ld8(qpA + 32);

    f32x4 oA[4] = {zero, zero, zero, zero};
    float lA[4] = {0.f, 0.f, 0.f, 0.f};
    const int ntiles = qb + 1;

#define STAGE(s0, buf)                                                         \
    do {                                                                       \
        const ushort_t* kg = Kb + (size_t)((s0) + lane) * 512 + kvb + wid * 8; \
        gl_lds16(kg,      Ks + (buf) * 4096 + wid * 512);                      \
        gl_lds16(kg + 32, Ks + (buf) * 4096 + (wid + 4) * 512);                \
        const ushort_t* vg = Vt + (size_t)(kvb + lane) * 2048 + (s0) + wid * 8;\
        gl_lds16(vg,      Vs + (buf) * 4096 + wid * 512);                      \
        gl_lds16(vg + 32, Vs + (buf) * 4096 + (wid + 4) * 512);                \
    } while (0)

#define COMPUTE(s0, buf)                                                       \
    do {                                                                       \
        f32x4 scA[4];                                                          \
        __builtin_amdgcn_s_setprio(1);                                         \
        _Pragma("unroll")                                                      \
        for (int cb = 0; cb < 4; cb++) {                                       \
            const bf16x8 kf0 = *(const bf16x8*)(Ks + (buf) * 4096 + quad * 512 + (cb * 16 + qn) * 8);       \
            const bf16x8 kf1 = *(const bf16x8*)(Ks + (buf) * 4096 + (quad + 4) * 512 + (cb * 16 + qn) * 8); \
            f32x4 s = mfma16(qA0, kf0, zero); scA[cb] = mfma16(qA1, kf1, s);   \
        }                                                                      \
        __builtin_amdgcn_s_setprio(0);                                         \
        const bool needmask = ((s0) + 63 > trow);                              \
        _Pragma("unroll")                                                      \
        for (int i = 0; i < 4; i++) {                                          \
            const int tA = trow + quad * 4 + i;                                \
            _Pragma("unroll")                                                  \
            for (int cb = 0; cb < 4; cb++) {                                   \
                const int col = (s0) + cb * 16 + qn;                           \
                float vA = scA[cb][i];                                         \
                if (needmask) {                                                \
                    if (col > tA) vA = -INFINITY;                              \
                }                                                              \
                const float pA = fexp2(vA);                                    \
                lA[i] += pA;                                                   \
                plw[(quad * 4 + i) * 72 + cb * 16 + qn] = f2b(pA);             \
            }                                                                  \
        }                                                                      \
        const bf16x8 pfA0 = *(const bf16x8*)(plw + qn * 72 + quad * 8);        \
        const bf16x8 pfA1 = *(const bf16x8*)(plw + qn * 72 + 32 + quad * 8);   \
        __builtin_amdgcn_s_setprio(1);                                         \
        _Pragma("unroll")                                                      \
        for (int dcb = 0; dcb < 4; dcb++) {                                    \
            const bf16x8 vf0 = *(const bf16x8*)(Vs + (buf) * 4096 + quad * 512 + (dcb * 16 + qn) * 8);       \
            const bf16x8 vf1 = *(const bf16x8*)(Vs + (buf) * 4096 + (quad + 4) * 512 + (dcb * 16 + qn) * 8); \
            oA[dcb] = mfma16(pfA0, vf0, oA[dcb]);                              \
            oA[dcb] = mfma16(pfA1, vf1, oA[dcb]);                              \
        }                                                                      \
        __builtin_amdgcn_s_setprio(0);                                         \
    } while (0)

    STAGE(0, 0);
    int t = 0;
    for (; t + 2 <= ntiles; t += 2) {
        __syncthreads();
        STAGE((t + 1) * 64, 1);
        COMPUTE(t * 64, 0);
        __syncthreads();
        if (t + 2 < ntiles) STAGE((t + 2) * 64, 0);
        COMPUTE((t + 1) * 64, 1);
    }
    if (t < ntiles) {                      // odd tail: buf0 already staged
        __syncthreads();
        COMPUTE(t * 64, 0);
    }
#undef STAGE
#undef COMPUTE

    #pragma unroll
    for (int i = 0; i < 4; i++) {
        float sA = lA[i];
        #pragma unroll
        for (int off = 1; off < 16; off <<= 1)
            sA += __shfl_xor(sA, off, 64);
        const float invA = 1.0f / sA;
        ushort_t* obA = Ob + (size_t)(trow + quad * 4 + i) * 2048 + h * 64 + qn;
        obA[0]  = f2b(oA[0][i] * invA);
        obA[16] = f2b(oA[1][i] * invA);
        obA[32] = f2b(oA[2][i] * invA);
        obA[48] = f2b(oA[3][i] * invA);
    }
}

// ---------- launch ----------
extern "C" void kernel_launch(void* const* d_in, const int* in_sizes, int n_in,
                              void* d_out, int out_size, void* d_ws, size_t ws_size,
                              hipStream_t stream) {
    const float* x    = (const float*)d_in[0];
    const float* cosp = (const float*)d_in[1];
    const float* sinp = (const float*)d_in[2];
    // d_in[3] = attention_mask_4d (pure causal; recomputed in-kernel)
    const float* Wq = (const float*)d_in[4];
    const float* Wk = (const float*)d_in[5];
    const float* Wv = (const float*)d_in[6];
    const float* Wo = (const float*)d_in[7];
    char* ws = (char*)d_ws;
    (void)ws_size; (void)in_sizes; (void)n_in; (void)out_size;

    ushort_t* xb    = (ushort_t*)(ws + WS_XB);
    ushort_t* wqkvb = (ushort_t*)(ws + WS_WQKV);
    ushort_t* wob   = (ushort_t*)(ws + WS_WO);
    ushort_t* p0    = (ushort_t*)(ws + WS_P0);
    ushort_t* p1    = (ushort_t*)(ws + WS_P1);
    ushort_t* qbb   = (ushort_t*)(ws + WS_QBB);
    ushort_t* kbb   = (ushort_t*)(ws + WS_KBB);
    ushort_t* vtg   = (ushort_t*)(ws + WS_VTG);
    ushort_t* ab    = (ushort_t*)(ws + WS_AB);
    float*    o0    = (float*)   (ws + WS_O0);
    float*    o1    = (float*)   (ws + WS_O1);

    // 1. convert inputs/weights to bf16 (contiguous dst: xb|wqkvb|wob)
    cvt_all<<<14336, 256, 0, stream>>>(x, Wq, Wk, Wv, Wo, xb);

    // 2. QKV projection split-K=2: 256^2 8-phase, 192 blocks (proven R8)
    gemm256<1><<<dim3(12, 8, 2), 512, 0, stream>>>(xb, wqkvb, p0, p1, 3072, 2048);

    // 3. fused combine + RoPE(q scale=(1/8)*log2e) + V transpose
    fuse_crv<<<dim3(48, 32), 256, 0, stream>>>(p0, p1, cosp, sinp, qbb, kbb, vtg);

    // 4. attention: 1024 blocks, 64 q-rows each
    attn_kernel<<<1024, 256, 0, stream>>>(qbb, kbb, vtg, ab);

    // 5. O-projection split-K=2: 256x128 8-phase, 256 blocks = 1/CU (proven R9)
    gemm_op<<<dim3(16, 8, 2), 512, 0, stream>>>(ab, wob, o0, o1, 2048, 2048);

    // 6. combine partials into fp32 output
    combine_o<<<2048, 256, 0, stream>>>((const float4*)o0, (const float4*)o1,
                                        (float4*)d_out);
}

// Round 11
// 243.031 us; speedup vs baseline: 1.2732x; 1.0321x over previous
//
#include <hip/hip_runtime.h>
#include <math.h>

// ---------- types ----------
typedef __attribute__((ext_vector_type(8))) __bf16 bf16x8;
typedef __attribute__((ext_vector_type(4))) float  f32x4;
typedef unsigned short ushort_t;
typedef unsigned int   uint_t;

static __device__ inline f32x4 mfma16(bf16x8 a, bf16x8 b, f32x4 c) {
    return __builtin_amdgcn_mfma_f32_16x16x32_bf16(a, b, c, 0, 0, 0);
}

static __device__ inline ushort_t f2b(float f) {
    uint_t u = __builtin_bit_cast(uint_t, f);
    u = (u + 0x7FFFu + ((u >> 16) & 1u)) >> 16;
    return (ushort_t)u;
}
static __device__ inline float b2f(ushort_t u) {
    uint_t x = ((uint_t)u) << 16;
    return __builtin_bit_cast(float, x);
}
static __device__ inline bf16x8 ld8(const ushort_t* p) {
    uint4 v = *(const uint4*)p;
    return __builtin_bit_cast(bf16x8, v);
}
static __device__ inline float fexp2(float x) {
#if __has_builtin(__builtin_amdgcn_exp2f)
    return __builtin_amdgcn_exp2f(x);
#else
    return exp2f(x);
#endif
}

// async global->LDS, 16B per lane; LDS dst = base + lane*16 (wave-uniform base!)
static __device__ inline void gl_lds16(const ushort_t* g, ushort_t* l) {
    __builtin_amdgcn_global_load_lds(
        (const __attribute__((address_space(1))) void*)(g),
        (__attribute__((address_space(3))) void*)(l),
        16, 0, 0);
}

// ---------- ws layout ----------
// R14: O-partials (o0/o1) no longer needed — gemm_on writes d_out directly.
#define WS_XB     0          //  8 MiB x bf16           [2048,2048]   (dead after QKV gemm)
#define WS_WQKV   8388608    // 12 MiB [Wq;Wk;Wv] bf16  [3072,2048]   (dead after QKV gemm)
#define WS_WO     20971520   //  8 MiB Wo bf16          [2048,2048]
#define WS_P0     29360128   // 12 MiB QKV partial 0 bf16 [2048,3072] (dead after fuse)
#define WS_P1     41943040   // 12 MiB QKV partial 1 bf16 [2048,3072] (dead after fuse)
#define WS_QBB    0          //  8 MiB q roped bf16     (overlays xb)
#define WS_KBB    8388608    //  2 MiB k roped bf16     (overlays wqkvb head)
#define WS_VTG    10485760   //  2 MiB V^T bf16 [512,2048]
#define WS_AB     12582912   //  8 MiB attn out bf16    (ends exactly at WS_WO)

// ---------- fp32 -> bf16 convert for x|Wq|Wk|Wv|Wo (contiguous dst) ----------
__global__ __launch_bounds__(256) void cvt_all(const float* __restrict__ x,
                                               const float* __restrict__ wq,
                                               const float* __restrict__ wk,
                                               const float* __restrict__ wv,
                                               const float* __restrict__ wo,
                                               ushort_t* __restrict__ dst) {
    const size_t i = (size_t)(blockIdx.x * 256 + threadIdx.x) * 4;
    const float* src; size_t off;
    if (i < 4194304)       { src = x;  off = 0; }
    else if (i < 8388608)  { src = wq; off = 4194304; }
    else if (i < 9437184)  { src = wk; off = 8388608; }
    else if (i < 10485760) { src = wv; off = 9437184; }
    else                   { src = wo; off = 10485760; }
    float4 v = *(const float4*)(src + (i - off));
    ushort4 o;
    o.x = f2b(v.x); o.y = f2b(v.y); o.z = f2b(v.z); o.w = f2b(v.w);
    *(ushort4*)(dst + i) = o;
}

// ---------- 256x256 8-phase GEMM (proven R8; QKV only) ----------
template <int OUTB>
__global__ __launch_bounds__(512, 2) void gemm256(const ushort_t* __restrict__ A,
                                                  const ushort_t* __restrict__ Bt,
                                                  void* __restrict__ C0,
                                                  void* __restrict__ C1,
                                                  int N, int K) {
    __shared__ ushort_t lds[65536];   // 128 KiB
    const int tid  = threadIdx.x;
    const int lane = tid & 63, w = tid >> 6;
    const int qn = lane & 15, quad = lane >> 4;
    const long m0 = (long)blockIdx.y * 256;
    const long n0 = (long)blockIdx.x * 256;
    const int kh   = K >> 1;
    const int kbeg = blockIdx.z * kh;
    const int NT   = kh >> 6;                  // even, >=4
    void* Cout = blockIdx.z ? C1 : C0;
    ushort_t* ldsp = lds;

    const int srow = w * 8 + (lane >> 3);
    const int scol = ((lane & 7) ^ (lane >> 3)) * 8;
    const ushort_t* gA = A  + (m0 + srow) * (size_t)K + kbeg + scol;
    const ushort_t* gB = Bt + (n0 + srow) * (size_t)K + kbeg + scol;

    const int aRow = ((w >> 2) * 64 + qn) * 64;
    const int bRow = ((w & 3) * 32 + qn) * 64;
    const int sw0 = ((quad * 16)      ^ ((qn & 7) << 4)) >> 1;   // ks=0
    const int sw1 = ((64 + quad * 16) ^ ((qn & 7) << 4)) >> 1;   // ks=1

#define STG_A(t, h, buf)                                                       \
    do { if ((t) < NT) {                                                       \
        const ushort_t* g = gA + (size_t)(h) * 128 * K + (t) * 64;             \
        ushort_t* d = ldsp + (buf) * 32768 + (h) * 8192 + w * 512;             \
        gl_lds16(g, d);                                                        \
        gl_lds16(g + 64 * (size_t)K, d + 4096);                                \
    } } while (0)
#define STG_B(t, h, buf)                                                       \
    do { if ((t) < NT) {                                                       \
        const ushort_t* g = gB + (size_t)(h) * 128 * K + (t) * 64;             \
        ushort_t* d = ldsp + (buf) * 32768 + 16384 + (h) * 8192 + w * 512;     \
        gl_lds16(g, d);                                                        \
        gl_lds16(g + 64 * (size_t)K, d + 4096);                                \
    } } while (0)

#define PHASE(cb, p, qr, qc, STAGE, BOUND)                                     \
    do {                                                                       \
        const ushort_t* bA = ldsp + (cb) * 32768 + (qr) * 8192;                \
        const ushort_t* bB = ldsp + (cb) * 32768 + 16384 + (qc) * 8192;        \
        bf16x8 af[4][2], bv[2][2];                                             \
        _Pragma("unroll")                                                      \
        for (int mi = 0; mi < 4; mi++) {                                       \
            af[mi][0] = *(const bf16x8*)(bA + aRow + mi * 1024 + sw0);         \
            af[mi][1] = *(const bf16x8*)(bA + aRow + mi * 1024 + sw1);         \
        }                                                                      \
        _Pragma("unroll")                                                      \
        for (int nj = 0; nj < 2; nj++) {                                       \
            bv[nj][0] = *(const bf16x8*)(bB + bRow + nj * 1024 + sw0);         \
            bv[nj][1] = *(const bf16x8*)(bB + bRow + nj * 1024 + sw1);         \
        }                                                                      \
        asm volatile("" ::: "memory");  /* pin reads above the stage */        \
        STAGE;                                                                 \
        BOUND;                                                                 \
        __builtin_amdgcn_s_barrier();                                          \
        asm volatile("s_waitcnt lgkmcnt(0)" ::: "memory");                     \
        __builtin_amdgcn_sched_barrier(0);                                     \
        __builtin_amdgcn_s_setprio(1);                                         \
        _Pragma("unroll")                                                      \
        for (int mi = 0; mi < 4; mi++)                                         \
            _Pragma("unroll")                                                  \
            for (int nj = 0; nj < 2; nj++) {                                   \
                acc[p][mi][nj] = mfma16(af[mi][0], bv[nj][0], acc[p][mi][nj]); \
                acc[p][mi][nj] = mfma16(af[mi][1], bv[nj][1], acc[p][mi][nj]); \
            }                                                                  \
        __builtin_amdgcn_s_setprio(0);                                         \
        __builtin_amdgcn_s_barrier();                                          \
    } while (0)

    f32x4 acc[4][4][2];
    f32x4 zero = {0.f, 0.f, 0.f, 0.f};
    #pragma unroll
    for (int p = 0; p < 4; p++)
        #pragma unroll
        for (int mi = 0; mi < 4; mi++)
            #pragma unroll
            for (int nj = 0; nj < 2; nj++) acc[p][mi][nj] = zero;

    STG_A(0, 0, 0); STG_B(0, 0, 0); STG_B(0, 1, 0); STG_A(0, 1, 0);
    STG_A(1, 0, 1); STG_B(1, 0, 1);
    asm volatile("s_waitcnt vmcnt(0)" ::: "memory");
    __builtin_amdgcn_s_barrier();

    for (int t2 = 0; t2 < NT; t2 += 2) {
        PHASE(0, 0, 0, 0, STG_B(t2 + 1, 1, 1), (void)0);
        PHASE(0, 1, 0, 1, STG_A(t2 + 1, 1, 1), (void)0);
        PHASE(0, 2, 1, 0, STG_A(t2 + 2, 0, 0), (void)0);
        PHASE(0, 3, 1, 1, STG_B(t2 + 2, 0, 0),
              if (t2 == NT - 2) { asm volatile("s_waitcnt vmcnt(0)" ::: "memory"); }
              else              { asm volatile("s_waitcnt vmcnt(4)" ::: "memory"); });
        PHASE(1, 0, 0, 0, STG_B(t2 + 2, 1, 0), (void)0);
        PHASE(1, 1, 0, 1, STG_A(t2 + 2, 1, 0), (void)0);
        PHASE(1, 2, 1, 0, STG_A(t2 + 3, 0, 1), (void)0);
        PHASE(1, 3, 1, 1, STG_B(t2 + 3, 0, 1),
              asm volatile("s_waitcnt vmcnt(4)" ::: "memory"););
    }
#undef PHASE
#undef STG_A
#undef STG_B

    #pragma unroll
    for (int p = 0; p < 4; p++) {
        const int qr = p >> 1, qc = p & 1;
        #pragma unroll
        for (int mi = 0; mi < 4; mi++)
            #pragma unroll
            for (int nj = 0; nj < 2; nj++) {
                const long row0 = m0 + qr * 128 + (w >> 2) * 64 + mi * 16 + quad * 4;
                const long col  = n0 + qc * 128 + (w & 3) * 32 + nj * 16 + qn;
                #pragma unroll
                for (int r = 0; r < 4; r++) {
                    if (OUTB)
                        ((ushort_t*)Cout)[(row0 + r) * N + col] = f2b(acc[p][mi][nj][r]);
                    else
                        ((float*)Cout)[(row0 + r) * N + col] = acc[p][mi][nj][r];
                }
            }
    }
}

// ---------- 256x64 full-K GEMM, direct fp32 out (O-projection; R14) ----------
// No split-K: grid (32,8) = 256 blocks = 1/CU; writes d_out directly, killing
// combine_o + the 48MB partial round-trip. 2 phases/tile (qr = A-half), 8
// waves as 4Mx2N over each 128x64 quadrant (wave tile 32x32; 8 MFMA : 8
// ds_read per phase — same shape as proven gemm_op phases). LDS 80 KiB =
// 2 buf x {A0 16K | A1 16K | B 8K}; B staged whole (1 gl_lds/wave — ledger
// stays wave-uniform). Stage stream: p0(t): A1(t+1)+B(t+1) -> buf^1 (last
// read p1(t-1)); p1(t): A0(t+2) -> buf (last read p0(t)). Ledger (drain-0
// prologue): before each p1-boundary: A0(t+1)[2] + A1(t+1)+B(t+1)[3] +
// A0(t+2)[2] = 7 outstanding; vmcnt(2) retires exactly tile t+1's 5.
// vmcnt(0) only at t==NT-2 (t+2 stage guarded out). NT >= 3.
__global__ __launch_bounds__(512, 2) void gemm_on(const ushort_t* __restrict__ A,
                                                  const ushort_t* __restrict__ Bt,
                                                  float* __restrict__ Cout,
                                                  int N, int K) {
    __shared__ ushort_t lds[40960];   // 80 KiB
    const int tid  = threadIdx.x;
    const int lane = tid & 63, w = tid >> 6;
    const int qn = lane & 15, quad = lane >> 4;
    const long m0 = (long)blockIdx.y * 256;
    const long n0 = (long)blockIdx.x * 64;
    const int NT = K >> 6;                    // 32
    ushort_t* ldsp = lds;

    const int srow = w * 8 + (lane >> 3);
    const int scol = ((lane & 7) ^ (lane >> 3)) * 8;
    const ushort_t* gA = A + (m0 + srow) * (size_t)K + scol;
    const int srB  = tid >> 3;
    const int scB  = ((tid & 7) ^ (srB & 7)) * 8;
    const ushort_t* gB = Bt + (n0 + srB) * (size_t)K + scB;

    const int wm = w >> 1, wn = w & 1;
    const int aRow = (wm * 32 + qn) * 64;
    const int bRow = (wn * 32 + qn) * 64;
    const int sw0 = ((quad * 16)      ^ ((qn & 7) << 4)) >> 1;
    const int sw1 = ((64 + quad * 16) ^ ((qn & 7) << 4)) >> 1;

#define NSTG_A(t, h, buf)                                                      \
    do { if ((t) < NT) {                                                       \
        const ushort_t* g = gA + (size_t)(h) * 128 * K + (t) * 64;             \
        ushort_t* d = ldsp + (buf) * 20480 + (h) * 8192 + w * 512;             \
        gl_lds16(g, d);                                                        \
        gl_lds16(g + 64 * (size_t)K, d + 4096);                                \
    } } while (0)
#define NSTG_B(t, buf)                                                         \
    do { if ((t) < NT) {                                                       \
        const ushort_t* g = gB + (size_t)(t) * 64;                             \
        ushort_t* d = ldsp + (buf) * 20480 + 16384 + w * 512;                  \
        gl_lds16(g, d);                                                        \
    } } while (0)

#define NPHASE(cb, qr, STAGE, BOUND)                                           \
    do {                                                                       \
        const ushort_t* bA = ldsp + (cb) * 20480 + (qr) * 8192;                \
        const ushort_t* bB = ldsp + (cb) * 20480 + 16384;                      \
        bf16x8 af[2][2], bv[2][2];                                             \
        _Pragma("unroll")                                                      \
        for (int mi = 0; mi < 2; mi++) {                                       \
            af[mi][0] = *(const bf16x8*)(bA + aRow + mi * 1024 + sw0);         \
            af[mi][1] = *(const bf16x8*)(bA + aRow + mi * 1024 + sw1);         \
        }                                                                      \
        _Pragma("unroll")                                                      \
        for (int nj = 0; nj < 2; nj++) {                                       \
            bv[nj][0] = *(const bf16x8*)(bB + bRow + nj * 1024 + sw0);         \
            bv[nj][1] = *(const bf16x8*)(bB + bRow + nj * 1024 + sw1);         \
        }                                                                      \
        asm volatile("" ::: "memory");                                         \
        STAGE;                                                                 \
        BOUND;                                                                 \
        __builtin_amdgcn_s_barrier();                                          \
        asm volatile("s_waitcnt lgkmcnt(0)" ::: "memory");                     \
        __builtin_amdgcn_sched_barrier(0);                                     \
        __builtin_amdgcn_s_setprio(1);                                         \
        _Pragma("unroll")                                                      \
        for (int mi = 0; mi < 2; mi++)                                         \
            _Pragma("unroll")                                                  \
            for (int nj = 0; nj < 2; nj++) {                                   \
                acc[qr][mi][nj] = mfma16(af[mi][0], bv[nj][0], acc[qr][mi][nj]); \
                acc[qr][mi][nj] = mfma16(af[mi][1], bv[nj][1], acc[qr][mi][nj]); \
            }                                                                  \
        __builtin_amdgcn_s_setprio(0);                                         \
        __builtin_amdgcn_s_barrier();                                          \
    } while (0)

    f32x4 acc[2][2][2];
    f32x4 zero = {0.f, 0.f, 0.f, 0.f};
    #pragma unroll
    for (int p = 0; p < 2; p++)
        #pragma unroll
        for (int mi = 0; mi < 2; mi++)
            #pragma unroll
            for (int nj = 0; nj < 2; nj++) acc[p][mi][nj] = zero;

    // prologue: tile 0 fully + A0(1); full drain (clean 0-outstanding start)
    NSTG_A(0, 0, 0); NSTG_A(0, 1, 0); NSTG_B(0, 0);
    NSTG_A(1, 0, 1);
    asm volatile("s_waitcnt vmcnt(0)" ::: "memory");
    __builtin_amdgcn_s_barrier();

    for (int t = 0; t < NT; t++) {
        const int cb = t & 1;
        NPHASE(cb, 0, { NSTG_A(t + 1, 1, cb ^ 1); NSTG_B(t + 1, cb ^ 1); },
               (void)0);
        NPHASE(cb, 1, { NSTG_A(t + 2, 0, cb); },
               if (t == NT - 2) { asm volatile("s_waitcnt vmcnt(0)" ::: "memory"); }
               else             { asm volatile("s_waitcnt vmcnt(2)" ::: "memory"); });
    }
#undef NPHASE
#undef NSTG_A
#undef NSTG_B

    #pragma unroll
    for (int p = 0; p < 2; p++)
        #pragma unroll
        for (int mi = 0; mi < 2; mi++)
            #pragma unroll
            for (int nj = 0; nj < 2; nj++) {
                const long row0 = m0 + p * 128 + wm * 32 + mi * 16 + quad * 4;
                const long col  = n0 + wn * 32 + nj * 16 + qn;
                #pragma unroll
                for (int r = 0; r < 4; r++)
                    Cout[(row0 + r) * N + col] = acc[p][mi][nj][r];
            }
}

// ---------- fused combine + RoPE + V-transpose (R1 verbatim) ----------
__global__ __launch_bounds__(256) void fuse_crv(const ushort_t* __restrict__ p0,
                                                const ushort_t* __restrict__ p1,
                                                const float* __restrict__ cs,
                                                const float* __restrict__ sn,
                                                ushort_t* __restrict__ qd,
                                                ushort_t* __restrict__ kd,
                                                ushort_t* __restrict__ vt) {
    __shared__ ushort_t tl[64][65];
    const int cx = blockIdx.x;               // 0..47
    const int ty = blockIdx.y;               // 0..31
    const int r  = threadIdx.x >> 2;         // 0..63
    const int c0 = (threadIdx.x & 3) << 4;   // 0,16,32,48
    const int t  = ty * 64 + r;
    const size_t base = (size_t)t * 3072 + cx * 64;

    if (cx < 40) {                           // q or k: combine + rope
        const int cp = c0 ^ 32;
        float own[16], par[16];
        #pragma unroll
        for (int jj = 0; jj < 2; jj++) {
            uint4 a = *(const uint4*)(p0 + base + c0 + jj * 8);
            uint4 b = *(const uint4*)(p1 + base + c0 + jj * 8);
            uint4 c = *(const uint4*)(p0 + base + cp + jj * 8);
            uint4 d = *(const uint4*)(p1 + base + cp + jj * 8);
            const ushort_t* pa = (const ushort_t*)&a;
            const ushort_t* pb = (const ushort_t*)&b;
            const ushort_t* pc = (const ushort_t*)&c;
            const ushort_t* pd = (const ushort_t*)&d;
            #pragma unroll
            for (int e = 0; e < 8; e++) {
                own[jj * 8 + e] = b2f(pa[e]) + b2f(pb[e]);
                par[jj * 8 + e] = b2f(pc[e]) + b2f(pd[e]);
            }
        }
        float cs16[16], sn16[16];
        #pragma unroll
        for (int jj = 0; jj < 4; jj++) {
            float4 c4 = *(const float4*)(cs + (size_t)t * 64 + c0 + jj * 4);
            float4 s4 = *(const float4*)(sn + (size_t)t * 64 + c0 + jj * 4);
            cs16[jj * 4 + 0] = c4.x; cs16[jj * 4 + 1] = c4.y;
            cs16[jj * 4 + 2] = c4.z; cs16[jj * 4 + 3] = c4.w;
            sn16[jj * 4 + 0] = s4.x; sn16[jj * 4 + 1] = s4.y;
            sn16[jj * 4 + 2] = s4.z; sn16[jj * 4 + 3] = s4.w;
        }
        const float scale = (cx < 32) ? 0.18033688f : 1.0f;  // q: (1/8)*log2e
        union { ushort_t u[16]; uint4 v[2]; } o;
        #pragma unroll
        for (int j = 0; j < 16; j++) {
            const int d = c0 + j;
            const float pr = (d < 32) ? -par[j] : par[j];
            o.u[j] = f2b((own[j] * cs16[j] + pr * sn16[j]) * scale);
        }
        if (cx < 32) {
            ushort_t* dst = qd + (size_t)t * 2048 + cx * 64 + c0;
            *(uint4*)dst = o.v[0]; *(uint4*)(dst + 8) = o.v[1];
        } else {
            ushort_t* dst = kd + (size_t)t * 512 + (cx - 32) * 64 + c0;
            *(uint4*)dst = o.v[0]; *(uint4*)(dst + 8) = o.v[1];
        }
    } else {                                 // v: combine + transpose via LDS
        #pragma unroll
        for (int jj = 0; jj < 2; jj++) {
            uint4 a = *(const uint4*)(p0 + base + c0 + jj * 8);
            uint4 b = *(const uint4*)(p1 + base + c0 + jj * 8);
            const ushort_t* pa = (const ushort_t*)&a;
            const ushort_t* pb = (const ushort_t*)&b;
            #pragma unroll
            for (int e = 0; e < 8; e++)
                tl[r][c0 + jj * 8 + e] = f2b(b2f(pa[e]) + b2f(pb[e]));
        }
        __syncthreads();
        const int rr  = threadIdx.x >> 3;        // 0..31
        const int cc8 = (threadIdx.x & 7) * 8;
        const int db = (cx - 40) * 64, tb = ty * 64;
        #pragma unroll
        for (int h = 0; h < 2; h++) {
            const int d = rr + h * 32;
            ushort4 o0, o1;
            o0.x = tl[cc8 + 0][d]; o0.y = tl[cc8 + 1][d];
            o0.z = tl[cc8 + 2][d]; o0.w = tl[cc8 + 3][d];
            o1.x = tl[cc8 + 4][d]; o1.y = tl[cc8 + 5][d];
            o1.z = tl[cc8 + 6][d]; o1.w = tl[cc8 + 7][d];
            *(ushort4*)(vt + (size_t)(db + d) * 2048 + tb + cc8)     = o0;
            *(ushort4*)(vt + (size_t)(db + d) * 2048 + tb + cc8 + 4) = o1;
        }
    }
}

// ---------- flash attention, causal, GQA G=4 (R10 verbatim: stride 72) ----------
__global__ __launch_bounds__(256) void attn_kernel(const ushort_t* __restrict__ Q,
                                                   const ushort_t* __restrict__ Kb,
                                                   const ushort_t* __restrict__ Vt,
                                                   ushort_t* __restrict__ Ob) {
    __shared__ ushort_t Ks[2 * 4096];     // 16 KB
    __shared__ ushort_t Vs[2 * 4096];     // 16 KB
    __shared__ ushort_t pl[4 * 16 * 72];  // 9 KB: per-wave P, 16 rows (stride 72)
    const int tid  = threadIdx.x;
    const int lane = tid & 63, wid = tid >> 6;
    const int qn = lane & 15, quad = lane >> 4;
    const int h   = blockIdx.x & 31;
    const int qb  = 31 - (blockIdx.x >> 5);     // heavy first, 0..31 (64-row blocks)
    const int kvb = (h >> 2) * 64;
    const int trow = qb * 64 + wid * 16;
    ushort_t* plw = pl + wid * 16 * 72;
    f32x4 zero = {0.f, 0.f, 0.f, 0.f};

    const ushort_t* qpA = Q + (size_t)(trow + qn) * 2048 + h * 64 + quad * 8;
    const bf16x8 qA0 = ld8(qpA), qA1 = ld8(qpA + 32);

    f32x4 oA[4] = {zero, zero, zero, zero};
    float lA[4] = {0.f, 0.f, 0.f, 0.f};
    const int ntiles = qb + 1;

#define STAGE(s0, buf)                                                         \
    do {                                                                       \
        const ushort_t* kg = Kb + (size_t)((s0) + lane) * 512 + kvb + wid * 8; \
        gl_lds16(kg,      Ks + (buf) * 4096 + wid * 512);                      \
        gl_lds16(kg + 32, Ks + (buf) * 4096 + (wid + 4) * 512);                \
        const ushort_t* vg = Vt + (size_t)(kvb + lane) * 2048 + (s0) + wid * 8;\
        gl_lds16(vg,      Vs + (buf) * 4096 + wid * 512);                      \
        gl_lds16(vg + 32, Vs + (buf) * 4096 + (wid + 4) * 512);                \
    } while (0)

#define COMPUTE(s0, buf)                                                       \
    do {                                                                       \
        f32x4 scA[4];                                                          \
        __builtin_amdgcn_s_setprio(1);                                         \
        _Pragma("unroll")                                                      \
        for (int cb = 0; cb < 4; cb++) {                                       \
            const bf16x8 kf0 = *(const bf16x8*)(Ks + (buf) * 4096 + quad * 512 + (cb * 16 + qn) * 8);       \
            const bf16x8 kf1 = *(const bf16x8*)(Ks + (buf) * 4096 + (quad + 4) * 512 + (cb * 16 + qn) * 8); \
            f32x4 s = mfma16(qA0, kf0, zero); scA[cb] = mfma16(qA1, kf1, s);   \
        }                                                                      \
        __builtin_amdgcn_s_setprio(0);                                         \
        const bool needmask = ((s0) + 63 > trow);                              \
        _Pragma("unroll")                                                      \
        for (int i = 0; i < 4; i++) {                                          \
            const int tA = trow + quad * 4 + i;                                \
            _Pragma("unroll")                                                  \
            for (int cb = 0; cb < 4; cb++) {                                   \
                const int col = (s0) + cb * 16 + qn;                           \
                float vA = scA[cb][i];                                         \
                if (needmask) {                                                \
                    if (col > tA) vA = -INFINITY;                              \
                }                                                              \
                const float pA = fexp2(vA);                                    \
                lA[i] += pA;                                                   \
                plw[(quad * 4 + i) * 72 + cb * 16 + qn] = f2b(pA);             \
            }                                                                  \
        }                                                                      \
        const bf16x8 pfA0 = *(const bf16x8*)(plw + qn * 72 + quad * 8);        \
        const bf16x8 pfA1 = *(const bf16x8*)(plw + qn * 72 + 32 + quad * 8);   \
        __builtin_amdgcn_s_setprio(1);                                         \
        _Pragma("unroll")                                                      \
        for (int dcb = 0; dcb < 4; dcb++) {                                    \
            const bf16x8 vf0 = *(const bf16x8*)(Vs + (buf) * 4096 + quad * 512 + (dcb * 16 + qn) * 8);       \
            const bf16x8 vf1 = *(const bf16x8*)(Vs + (buf) * 4096 + (quad + 4) * 512 + (dcb * 16 + qn) * 8); \
            oA[dcb] = mfma16(pfA0, vf0, oA[dcb]);                              \
            oA[dcb] = mfma16(pfA1, vf1, oA[dcb]);                              \
        }                                                                      \
        __builtin_amdgcn_s_setprio(0);                                         \
    } while (0)

    STAGE(0, 0);
    int t = 0;
    for (; t + 2 <= ntiles; t += 2) {
        __syncthreads();
        STAGE((t + 1) * 64, 1);
        COMPUTE(t * 64, 0);
        __syncthreads();
        if (t + 2 < ntiles) STAGE((t + 2) * 64, 0);
        COMPUTE((t + 1) * 64, 1);
    }
    if (t < ntiles) {                      // odd tail: buf0 already staged
        __syncthreads();
        COMPUTE(t * 64, 0);
    }
#undef STAGE
#undef COMPUTE

    #pragma unroll
    for (int i = 0; i < 4; i++) {
        float sA = lA[i];
        #pragma unroll
        for (int off = 1; off < 16; off <<= 1)
            sA += __shfl_xor(sA, off, 64);
        const float invA = 1.0f / sA;
        ushort_t* obA = Ob + (size_t)(trow + quad * 4 + i) * 2048 + h * 64 + qn;
        obA[0]  = f2b(oA[0][i] * invA);
        obA[16] = f2b(oA[1][i] * invA);
        obA[32] = f2b(oA[2][i] * invA);
        obA[48] = f2b(oA[3][i] * invA);
    }
}

// ---------- launch ----------
extern "C" void kernel_launch(void* const* d_in, const int* in_sizes, int n_in,
                              void* d_out, int out_size, void* d_ws, size_t ws_size,
                              hipStream_t stream) {
    const float* x    = (const float*)d_in[0];
    const float* cosp = (const float*)d_in[1];
    const float* sinp = (const float*)d_in[2];
    // d_in[3] = attention_mask_4d (pure causal; recomputed in-kernel)
    const float* Wq = (const float*)d_in[4];
    const float* Wk = (const float*)d_in[5];
    const float* Wv = (const float*)d_in[6];
    const float* Wo = (const float*)d_in[7];
    char* ws = (char*)d_ws;
    (void)ws_size; (void)in_sizes; (void)n_in; (void)out_size;

    ushort_t* xb    = (ushort_t*)(ws + WS_XB);
    ushort_t* wqkvb = (ushort_t*)(ws + WS_WQKV);
    ushort_t* wob   = (ushort_t*)(ws + WS_WO);
    ushort_t* p0    = (ushort_t*)(ws + WS_P0);
    ushort_t* p1    = (ushort_t*)(ws + WS_P1);
    ushort_t* qbb   = (ushort_t*)(ws + WS_QBB);
    ushort_t* kbb   = (ushort_t*)(ws + WS_KBB);
    ushort_t* vtg   = (ushort_t*)(ws + WS_VTG);
    ushort_t* ab    = (ushort_t*)(ws + WS_AB);

    // 1. convert inputs/weights to bf16 (contiguous dst: xb|wqkvb|wob)
    cvt_all<<<14336, 256, 0, stream>>>(x, Wq, Wk, Wv, Wo, xb);

    // 2. QKV projection split-K=2: 256^2 8-phase, 192 blocks (proven R8)
    gemm256<1><<<dim3(12, 8, 2), 512, 0, stream>>>(xb, wqkvb, p0, p1, 3072, 2048);

    // 3. fused combine + RoPE(q scale=(1/8)*log2e) + V transpose
    fuse_crv<<<dim3(48, 32), 256, 0, stream>>>(p0, p1, cosp, sinp, qbb, kbb, vtg);

    // 4. attention: 1024 blocks, 64 q-rows each (R10 verbatim)
    attn_kernel<<<1024, 256, 0, stream>>>(qbb, kbb, vtg, ab);

    // 5. O-projection: 256x64 full-K, 256 blocks = 1/CU, direct fp32 out
    //    (kills combine_o + 48MB of partial-slab traffic)
    gemm_on<<<dim3(32, 8), 512, 0, stream>>>(ab, wob, (float*)d_out, 2048, 2048);
}

// Round 12
// 237.975 us; speedup vs baseline: 1.3003x; 1.0212x over previous
//
#include <hip/hip_runtime.h>
#include <math.h>

// ---------- types ----------
typedef __attribute__((ext_vector_type(8))) __bf16 bf16x8;
typedef __attribute__((ext_vector_type(4))) float  f32x4;
typedef unsigned short ushort_t;
typedef unsigned int   uint_t;

static __device__ inline f32x4 mfma16(bf16x8 a, bf16x8 b, f32x4 c) {
    return __builtin_amdgcn_mfma_f32_16x16x32_bf16(a, b, c, 0, 0, 0);
}

static __device__ inline ushort_t f2b(float f) {
    uint_t u = __builtin_bit_cast(uint_t, f);
    u = (u + 0x7FFFu + ((u >> 16) & 1u)) >> 16;
    return (ushort_t)u;
}
static __device__ inline float b2f(ushort_t u) {
    uint_t x = ((uint_t)u) << 16;
    return __builtin_bit_cast(float, x);
}
static __device__ inline bf16x8 ld8(const ushort_t* p) {
    uint4 v = *(const uint4*)p;
    return __builtin_bit_cast(bf16x8, v);
}
static __device__ inline float fexp2(float x) {
#if __has_builtin(__builtin_amdgcn_exp2f)
    return __builtin_amdgcn_exp2f(x);
#else
    return exp2f(x);
#endif
}

// async global->LDS, 16B per lane; LDS dst = base + lane*16 (wave-uniform base!)
static __device__ inline void gl_lds16(const ushort_t* g, ushort_t* l) {
    __builtin_amdgcn_global_load_lds(
        (const __attribute__((address_space(1))) void*)(g),
        (__attribute__((address_space(3))) void*)(l),
        16, 0, 0);
}

// ---------- ws layout ----------
#define WS_XB     0          //  8 MiB x bf16           [2048,2048]   (dead after QKV gemm)
#define WS_WQKV   8388608    // 12 MiB [Wq;Wk;Wv] bf16  [3072,2048]   (dead after QKV gemm)
#define WS_WO     20971520   //  8 MiB Wo bf16          [2048,2048]
#define WS_P0     29360128   // 12 MiB QKV partial 0 bf16 [2048,3072] (dead after fuse)
#define WS_P1     41943040   // 12 MiB QKV partial 1 bf16 [2048,3072] (dead after fuse)
#define WS_QBB    0          //  8 MiB q roped bf16     (overlays xb)
#define WS_KBB    8388608    //  2 MiB k roped bf16     (overlays wqkvb head)
#define WS_VTG    10485760   //  2 MiB V^T bf16 [512,2048]
#define WS_AB     12582912   //  8 MiB attn out bf16    (ends exactly at WS_WO)

// ---------- fp32 -> bf16 convert for x|Wq|Wk|Wv|Wo (contiguous dst) ----------
__global__ __launch_bounds__(256) void cvt_all(const float* __restrict__ x,
                                               const float* __restrict__ wq,
                                               const float* __restrict__ wk,
                                               const float* __restrict__ wv,
                                               const float* __restrict__ wo,
                                               ushort_t* __restrict__ dst) {
    const size_t i = (size_t)(blockIdx.x * 256 + threadIdx.x) * 4;
    const float* src; size_t off;
    if (i < 4194304)       { src = x;  off = 0; }
    else if (i < 8388608)  { src = wq; off = 4194304; }
    else if (i < 9437184)  { src = wk; off = 8388608; }
    else if (i < 10485760) { src = wv; off = 9437184; }
    else                   { src = wo; off = 10485760; }
    float4 v = *(const float4*)(src + (i - off));
    ushort4 o;
    o.x = f2b(v.x); o.y = f2b(v.y); o.z = f2b(v.z); o.w = f2b(v.w);
    *(ushort4*)(dst + i) = o;
}

// ---------- 256x256 8-phase GEMM (proven R8; QKV only) ----------
template <int OUTB>
__global__ __launch_bounds__(512, 2) void gemm256(const ushort_t* __restrict__ A,
                                                  const ushort_t* __restrict__ Bt,
                                                  void* __restrict__ C0,
                                                  void* __restrict__ C1,
                                                  int N, int K) {
    __shared__ ushort_t lds[65536];   // 128 KiB
    const int tid  = threadIdx.x;
    const int lane = tid & 63, w = tid >> 6;
    const int qn = lane & 15, quad = lane >> 4;
    const long m0 = (long)blockIdx.y * 256;
    const long n0 = (long)blockIdx.x * 256;
    const int kh   = K >> 1;
    const int kbeg = blockIdx.z * kh;
    const int NT   = kh >> 6;                  // even, >=4
    void* Cout = blockIdx.z ? C1 : C0;
    ushort_t* ldsp = lds;

    const int srow = w * 8 + (lane >> 3);
    const int scol = ((lane & 7) ^ (lane >> 3)) * 8;
    const ushort_t* gA = A  + (m0 + srow) * (size_t)K + kbeg + scol;
    const ushort_t* gB = Bt + (n0 + srow) * (size_t)K + kbeg + scol;

    const int aRow = ((w >> 2) * 64 + qn) * 64;
    const int bRow = ((w & 3) * 32 + qn) * 64;
    const int sw0 = ((quad * 16)      ^ ((qn & 7) << 4)) >> 1;   // ks=0
    const int sw1 = ((64 + quad * 16) ^ ((qn & 7) << 4)) >> 1;   // ks=1

#define STG_A(t, h, buf)                                                       \
    do { if ((t) < NT) {                                                       \
        const ushort_t* g = gA + (size_t)(h) * 128 * K + (t) * 64;             \
        ushort_t* d = ldsp + (buf) * 32768 + (h) * 8192 + w * 512;             \
        gl_lds16(g, d);                                                        \
        gl_lds16(g + 64 * (size_t)K, d + 4096);                                \
    } } while (0)
#define STG_B(t, h, buf)                                                       \
    do { if ((t) < NT) {                                                       \
        const ushort_t* g = gB + (size_t)(h) * 128 * K + (t) * 64;             \
        ushort_t* d = ldsp + (buf) * 32768 + 16384 + (h) * 8192 + w * 512;     \
        gl_lds16(g, d);                                                        \
        gl_lds16(g + 64 * (size_t)K, d + 4096);                                \
    } } while (0)

#define PHASE(cb, p, qr, qc, STAGE, BOUND)                                     \
    do {                                                                       \
        const ushort_t* bA = ldsp + (cb) * 32768 + (qr) * 8192;                \
        const ushort_t* bB = ldsp + (cb) * 32768 + 16384 + (qc) * 8192;        \
        bf16x8 af[4][2], bv[2][2];                                             \
        _Pragma("unroll")                                                      \
        for (int mi = 0; mi < 4; mi++) {                                       \
            af[mi][0] = *(const bf16x8*)(bA + aRow + mi * 1024 + sw0);         \
            af[mi][1] = *(const bf16x8*)(bA + aRow + mi * 1024 + sw1);         \
        }                                                                      \
        _Pragma("unroll")                                                      \
        for (int nj = 0; nj < 2; nj++) {                                       \
            bv[nj][0] = *(const bf16x8*)(bB + bRow + nj * 1024 + sw0);         \
            bv[nj][1] = *(const bf16x8*)(bB + bRow + nj * 1024 + sw1);         \
        }                                                                      \
        asm volatile("" ::: "memory");  /* pin reads above the stage */        \
        STAGE;                                                                 \
        BOUND;                                                                 \
        __builtin_amdgcn_s_barrier();                                          \
        asm volatile("s_waitcnt lgkmcnt(0)" ::: "memory");                     \
        __builtin_amdgcn_sched_barrier(0);                                     \
        __builtin_amdgcn_s_setprio(1);                                         \
        _Pragma("unroll")                                                      \
        for (int mi = 0; mi < 4; mi++)                                         \
            _Pragma("unroll")                                                  \
            for (int nj = 0; nj < 2; nj++) {                                   \
                acc[p][mi][nj] = mfma16(af[mi][0], bv[nj][0], acc[p][mi][nj]); \
                acc[p][mi][nj] = mfma16(af[mi][1], bv[nj][1], acc[p][mi][nj]); \
            }                                                                  \
        __builtin_amdgcn_s_setprio(0);                                         \
        __builtin_amdgcn_s_barrier();                                          \
    } while (0)

    f32x4 acc[4][4][2];
    f32x4 zero = {0.f, 0.f, 0.f, 0.f};
    #pragma unroll
    for (int p = 0; p < 4; p++)
        #pragma unroll
        for (int mi = 0; mi < 4; mi++)
            #pragma unroll
            for (int nj = 0; nj < 2; nj++) acc[p][mi][nj] = zero;

    STG_A(0, 0, 0); STG_B(0, 0, 0); STG_B(0, 1, 0); STG_A(0, 1, 0);
    STG_A(1, 0, 1); STG_B(1, 0, 1);
    asm volatile("s_waitcnt vmcnt(0)" ::: "memory");
    __builtin_amdgcn_s_barrier();

    for (int t2 = 0; t2 < NT; t2 += 2) {
        PHASE(0, 0, 0, 0, STG_B(t2 + 1, 1, 1), (void)0);
        PHASE(0, 1, 0, 1, STG_A(t2 + 1, 1, 1), (void)0);
        PHASE(0, 2, 1, 0, STG_A(t2 + 2, 0, 0), (void)0);
        PHASE(0, 3, 1, 1, STG_B(t2 + 2, 0, 0),
              if (t2 == NT - 2) { asm volatile("s_waitcnt vmcnt(0)" ::: "memory"); }
              else              { asm volatile("s_waitcnt vmcnt(4)" ::: "memory"); });
        PHASE(1, 0, 0, 0, STG_B(t2 + 2, 1, 0), (void)0);
        PHASE(1, 1, 0, 1, STG_A(t2 + 2, 1, 0), (void)0);
        PHASE(1, 2, 1, 0, STG_A(t2 + 3, 0, 1), (void)0);
        PHASE(1, 3, 1, 1, STG_B(t2 + 3, 0, 1),
              asm volatile("s_waitcnt vmcnt(4)" ::: "memory"););
    }
#undef PHASE
#undef STG_A
#undef STG_B

    #pragma unroll
    for (int p = 0; p < 4; p++) {
        const int qr = p >> 1, qc = p & 1;
        #pragma unroll
        for (int mi = 0; mi < 4; mi++)
            #pragma unroll
            for (int nj = 0; nj < 2; nj++) {
                const long row0 = m0 + qr * 128 + (w >> 2) * 64 + mi * 16 + quad * 4;
                const long col  = n0 + qc * 128 + (w & 3) * 32 + nj * 16 + qn;
                #pragma unroll
                for (int r = 0; r < 4; r++) {
                    if (OUTB)
                        ((ushort_t*)Cout)[(row0 + r) * N + col] = f2b(acc[p][mi][nj][r]);
                    else
                        ((float*)Cout)[(row0 + r) * N + col] = acc[p][mi][nj][r];
                }
            }
    }
}

// ---------- 256x64 full-K GEMM, direct fp32 out (O-projection; proven R11) ----------
__global__ __launch_bounds__(512, 2) void gemm_on(const ushort_t* __restrict__ A,
                                                  const ushort_t* __restrict__ Bt,
                                                  float* __restrict__ Cout,
                                                  int N, int K) {
    __shared__ ushort_t lds[40960];   // 80 KiB
    const int tid  = threadIdx.x;
    const int lane = tid & 63, w = tid >> 6;
    const int qn = lane & 15, quad = lane >> 4;
    const long m0 = (long)blockIdx.y * 256;
    const long n0 = (long)blockIdx.x * 64;
    const int NT = K >> 6;                    // 32
    ushort_t* ldsp = lds;

    const int srow = w * 8 + (lane >> 3);
    const int scol = ((lane & 7) ^ (lane >> 3)) * 8;
    const ushort_t* gA = A + (m0 + srow) * (size_t)K + scol;
    const int srB  = tid >> 3;
    const int scB  = ((tid & 7) ^ (srB & 7)) * 8;
    const ushort_t* gB = Bt + (n0 + srB) * (size_t)K + scB;

    const int wm = w >> 1, wn = w & 1;
    const int aRow = (wm * 32 + qn) * 64;
    const int bRow = (wn * 32 + qn) * 64;
    const int sw0 = ((quad * 16)      ^ ((qn & 7) << 4)) >> 1;
    const int sw1 = ((64 + quad * 16) ^ ((qn & 7) << 4)) >> 1;

#define NSTG_A(t, h, buf)                                                      \
    do { if ((t) < NT) {                                                       \
        const ushort_t* g = gA + (size_t)(h) * 128 * K + (t) * 64;             \
        ushort_t* d = ldsp + (buf) * 20480 + (h) * 8192 + w * 512;             \
        gl_lds16(g, d);                                                        \
        gl_lds16(g + 64 * (size_t)K, d + 4096);                                \
    } } while (0)
#define NSTG_B(t, buf)                                                         \
    do { if ((t) < NT) {                                                       \
        const ushort_t* g = gB + (size_t)(t) * 64;                             \
        ushort_t* d = ldsp + (buf) * 20480 + 16384 + w * 512;                  \
        gl_lds16(g, d);                                                        \
    } } while (0)

#define NPHASE(cb, qr, STAGE, BOUND)                                           \
    do {                                                                       \
        const ushort_t* bA = ldsp + (cb) * 20480 + (qr) * 8192;                \
        const ushort_t* bB = ldsp + (cb) * 20480 + 16384;                      \
        bf16x8 af[2][2], bv[2][2];                                             \
        _Pragma("unroll")                                                      \
        for (int mi = 0; mi < 2; mi++) {                                       \
            af[mi][0] = *(const bf16x8*)(bA + aRow + mi * 1024 + sw0);         \
            af[mi][1] = *(const bf16x8*)(bA + aRow + mi * 1024 + sw1);         \
        }                                                                      \
        _Pragma("unroll")                                                      \
        for (int nj = 0; nj < 2; nj++) {                                       \
            bv[nj][0] = *(const bf16x8*)(bB + bRow + nj * 1024 + sw0);         \
            bv[nj][1] = *(const bf16x8*)(bB + bRow + nj * 1024 + sw1);         \
        }                                                                      \
        asm volatile("" ::: "memory");                                         \
        STAGE;                                                                 \
        BOUND;                                                                 \
        __builtin_amdgcn_s_barrier();                                          \
        asm volatile("s_waitcnt lgkmcnt(0)" ::: "memory");                     \
        __builtin_amdgcn_sched_barrier(0);                                     \
        __builtin_amdgcn_s_setprio(1);                                         \
        _Pragma("unroll")                                                      \
        for (int mi = 0; mi < 2; mi++)                                         \
            _Pragma("unroll")                                                  \
            for (int nj = 0; nj < 2; nj++) {                                   \
                acc[qr][mi][nj] = mfma16(af[mi][0], bv[nj][0], acc[qr][mi][nj]); \
                acc[qr][mi][nj] = mfma16(af[mi][1], bv[nj][1], acc[qr][mi][nj]); \
            }                                                                  \
        __builtin_amdgcn_s_setprio(0);                                         \
        __builtin_amdgcn_s_barrier();                                          \
    } while (0)

    f32x4 acc[2][2][2];
    f32x4 zero = {0.f, 0.f, 0.f, 0.f};
    #pragma unroll
    for (int p = 0; p < 2; p++)
        #pragma unroll
        for (int mi = 0; mi < 2; mi++)
            #pragma unroll
            for (int nj = 0; nj < 2; nj++) acc[p][mi][nj] = zero;

    NSTG_A(0, 0, 0); NSTG_A(0, 1, 0); NSTG_B(0, 0);
    NSTG_A(1, 0, 1);
    asm volatile("s_waitcnt vmcnt(0)" ::: "memory");
    __builtin_amdgcn_s_barrier();

    for (int t = 0; t < NT; t++) {
        const int cb = t & 1;
        NPHASE(cb, 0, { NSTG_A(t + 1, 1, cb ^ 1); NSTG_B(t + 1, cb ^ 1); },
               (void)0);
        NPHASE(cb, 1, { NSTG_A(t + 2, 0, cb); },
               if (t == NT - 2) { asm volatile("s_waitcnt vmcnt(0)" ::: "memory"); }
               else             { asm volatile("s_waitcnt vmcnt(2)" ::: "memory"); });
    }
#undef NPHASE
#undef NSTG_A
#undef NSTG_B

    #pragma unroll
    for (int p = 0; p < 2; p++)
        #pragma unroll
        for (int mi = 0; mi < 2; mi++)
            #pragma unroll
            for (int nj = 0; nj < 2; nj++) {
                const long row0 = m0 + p * 128 + wm * 32 + mi * 16 + quad * 4;
                const long col  = n0 + wn * 32 + nj * 16 + qn;
                #pragma unroll
                for (int r = 0; r < 4; r++)
                    Cout[(row0 + r) * N + col] = acc[p][mi][nj][r];
            }
}

// ---------- fused combine + RoPE + V-transpose (R1 verbatim) ----------
__global__ __launch_bounds__(256) void fuse_crv(const ushort_t* __restrict__ p0,
                                                const ushort_t* __restrict__ p1,
                                                const float* __restrict__ cs,
                                                const float* __restrict__ sn,
                                                ushort_t* __restrict__ qd,
                                                ushort_t* __restrict__ kd,
                                                ushort_t* __restrict__ vt) {
    __shared__ ushort_t tl[64][65];
    const int cx = blockIdx.x;               // 0..47
    const int ty = blockIdx.y;               // 0..31
    const int r  = threadIdx.x >> 2;         // 0..63
    const int c0 = (threadIdx.x & 3) << 4;   // 0,16,32,48
    const int t  = ty * 64 + r;
    const size_t base = (size_t)t * 3072 + cx * 64;

    if (cx < 40) {                           // q or k: combine + rope
        const int cp = c0 ^ 32;
        float own[16], par[16];
        #pragma unroll
        for (int jj = 0; jj < 2; jj++) {
            uint4 a = *(const uint4*)(p0 + base + c0 + jj * 8);
            uint4 b = *(const uint4*)(p1 + base + c0 + jj * 8);
            uint4 c = *(const uint4*)(p0 + base + cp + jj * 8);
            uint4 d = *(const uint4*)(p1 + base + cp + jj * 8);
            const ushort_t* pa = (const ushort_t*)&a;
            const ushort_t* pb = (const ushort_t*)&b;
            const ushort_t* pc = (const ushort_t*)&c;
            const ushort_t* pd = (const ushort_t*)&d;
            #pragma unroll
            for (int e = 0; e < 8; e++) {
                own[jj * 8 + e] = b2f(pa[e]) + b2f(pb[e]);
                par[jj * 8 + e] = b2f(pc[e]) + b2f(pd[e]);
            }
        }
        float cs16[16], sn16[16];
        #pragma unroll
        for (int jj = 0; jj < 4; jj++) {
            float4 c4 = *(const float4*)(cs + (size_t)t * 64 + c0 + jj * 4);
            float4 s4 = *(const float4*)(sn + (size_t)t * 64 + c0 + jj * 4);
            cs16[jj * 4 + 0] = c4.x; cs16[jj * 4 + 1] = c4.y;
            cs16[jj * 4 + 2] = c4.z; cs16[jj * 4 + 3] = c4.w;
            sn16[jj * 4 + 0] = s4.x; sn16[jj * 4 + 1] = s4.y;
            sn16[jj * 4 + 2] = s4.z; sn16[jj * 4 + 3] = s4.w;
        }
        const float scale = (cx < 32) ? 0.18033688f : 1.0f;  // q: (1/8)*log2e
        union { ushort_t u[16]; uint4 v[2]; } o;
        #pragma unroll
        for (int j = 0; j < 16; j++) {
            const int d = c0 + j;
            const float pr = (d < 32) ? -par[j] : par[j];
            o.u[j] = f2b((own[j] * cs16[j] + pr * sn16[j]) * scale);
        }
        if (cx < 32) {
            ushort_t* dst = qd + (size_t)t * 2048 + cx * 64 + c0;
            *(uint4*)dst = o.v[0]; *(uint4*)(dst + 8) = o.v[1];
        } else {
            ushort_t* dst = kd + (size_t)t * 512 + (cx - 32) * 64 + c0;
            *(uint4*)dst = o.v[0]; *(uint4*)(dst + 8) = o.v[1];
        }
    } else {                                 // v: combine + transpose via LDS
        #pragma unroll
        for (int jj = 0; jj < 2; jj++) {
            uint4 a = *(const uint4*)(p0 + base + c0 + jj * 8);
            uint4 b = *(const uint4*)(p1 + base + c0 + jj * 8);
            const ushort_t* pa = (const ushort_t*)&a;
            const ushort_t* pb = (const ushort_t*)&b;
            #pragma unroll
            for (int e = 0; e < 8; e++)
                tl[r][c0 + jj * 8 + e] = f2b(b2f(pa[e]) + b2f(pb[e]));
        }
        __syncthreads();
        const int rr  = threadIdx.x >> 3;        // 0..31
        const int cc8 = (threadIdx.x & 7) * 8;
        const int db = (cx - 40) * 64, tb = ty * 64;
        #pragma unroll
        for (int h = 0; h < 2; h++) {
            const int d = rr + h * 32;
            ushort4 o0, o1;
            o0.x = tl[cc8 + 0][d]; o0.y = tl[cc8 + 1][d];
            o0.z = tl[cc8 + 2][d]; o0.w = tl[cc8 + 3][d];
            o1.x = tl[cc8 + 4][d]; o1.y = tl[cc8 + 5][d];
            o1.z = tl[cc8 + 6][d]; o1.w = tl[cc8 + 7][d];
            *(ushort4*)(vt + (size_t)(db + d) * 2048 + tb + cc8)     = o0;
            *(ushort4*)(vt + (size_t)(db + d) * 2048 + tb + cc8 + 4) = o1;
        }
    }
}

// ---------- flash attention, causal, GQA G=4 ----------
// R15: swapped QK^T (T12 mechanism, 16x16 form). A/B fragment layouts of
// mfma_f32_16x16x32_bf16 are symmetric ([idx][k] row-major), so
// mfma16(kf, qA, .) transposes the score tile: lane holds
// S[q=trow+qn][k=s0+cb*16+quad*4+r] — 4 ADJACENT k-cols. Enables:
//   * 8x v_cvt_pk_bf16_f32 (inline asm; no builtin, m240) replacing 16x
//     3-op f2b (-40 VALU instrs/tile);
//   * 4x 8B P-writes (uint2; word = 4qn+2quad mod 32 -> 2-way, free)
//     replacing 16 scalar b16 writes;
//   * single lsum accumulator; row-sum via shfl_xor(16,32) + per-i shfl.
// P LDS layout [q-row][k] (stride 72) and the PV read path are UNCHANGED.
__global__ __launch_bounds__(256) void attn_kernel(const ushort_t* __restrict__ Q,
                                                   const ushort_t* __restrict__ Kb,
                                                   const ushort_t* __restrict__ Vt,
                                                   ushort_t* __restrict__ Ob) {
    __shared__ ushort_t Ks[2 * 4096];     // 16 KB
    __shared__ ushort_t Vs[2 * 4096];     // 16 KB
    __shared__ ushort_t pl[4 * 16 * 72];  // 9 KB: per-wave P, 16 rows (stride 72)
    const int tid  = threadIdx.x;
    const int lane = tid & 63, wid = tid >> 6;
    const int qn = lane & 15, quad = lane >> 4;
    const int h   = blockIdx.x & 31;
    const int qb  = 31 - (blockIdx.x >> 5);     // heavy first, 0..31 (64-row blocks)
    const int kvb = (h >> 2) * 64;
    const int trow = qb * 64 + wid * 16;
    ushort_t* plw = pl + wid * 16 * 72;
    f32x4 zero = {0.f, 0.f, 0.f, 0.f};

    const ushort_t* qpA = Q + (size_t)(trow + qn) * 2048 + h * 64 + quad * 8;
    const bf16x8 qA0 = ld8(qpA), qA1 = ld8(qpA + 32);

    f32x4 oA[4] = {zero, zero, zero, zero};
    float lsum = 0.f;
    const int ntiles = qb + 1;

#define STAGE(s0, buf)                                                         \
    do {                                                                       \
        const ushort_t* kg = Kb + (size_t)((s0) + lane) * 512 + kvb + wid * 8; \
        gl_lds16(kg,      Ks + (buf) * 4096 + wid * 512);                      \
        gl_lds16(kg + 32, Ks + (buf) * 4096 + (wid + 4) * 512);                \
        const ushort_t* vg = Vt + (size_t)(kvb + lane) * 2048 + (s0) + wid * 8;\
        gl_lds16(vg,      Vs + (buf) * 4096 + wid * 512);                      \
        gl_lds16(vg + 32, Vs + (buf) * 4096 + (wid + 4) * 512);                \
    } while (0)

#define COMPUTE(s0, buf)                                                       \
    do {                                                                       \
        f32x4 scA[4];                                                          \
        __builtin_amdgcn_s_setprio(1);                                         \
        _Pragma("unroll")                                                      \
        for (int cb = 0; cb < 4; cb++) {                                       \
            const bf16x8 kf0 = *(const bf16x8*)(Ks + (buf) * 4096 + quad * 512 + (cb * 16 + qn) * 8);       \
            const bf16x8 kf1 = *(const bf16x8*)(Ks + (buf) * 4096 + (quad + 4) * 512 + (cb * 16 + qn) * 8); \
            f32x4 s = mfma16(kf0, qA0, zero); scA[cb] = mfma16(kf1, qA1, s);   \
        }                                                                      \
        __builtin_amdgcn_s_setprio(0);                                         \
        const bool needmask = ((s0) + 63 > trow);                              \
        const int tA = trow + qn;                                              \
        _Pragma("unroll")                                                      \
        for (int cb = 0; cb < 4; cb++) {                                       \
            float pv0, pv1, pv2, pv3;                                          \
            {                                                                  \
                const int colb = (s0) + cb * 16 + quad * 4;                    \
                float v0 = scA[cb][0], v1 = scA[cb][1];                        \
                float v2 = scA[cb][2], v3 = scA[cb][3];                        \
                if (needmask) {                                                \
                    if (colb + 0 > tA) v0 = -INFINITY;                         \
                    if (colb + 1 > tA) v1 = -INFINITY;                         \
                    if (colb + 2 > tA) v2 = -INFINITY;                         \
                    if (colb + 3 > tA) v3 = -INFINITY;                         \
                }                                                              \
                pv0 = fexp2(v0); pv1 = fexp2(v1);                              \
                pv2 = fexp2(v2); pv3 = fexp2(v3);                              \
            }                                                                  \
            lsum += pv0 + pv1 + pv2 + pv3;                                     \
            uint_t w0, w1;                                                     \
            asm("v_cvt_pk_bf16_f32 %0, %1, %2" : "=v"(w0) : "v"(pv0), "v"(pv1)); \
            asm("v_cvt_pk_bf16_f32 %0, %1, %2" : "=v"(w1) : "v"(pv2), "v"(pv3)); \
            uint2 pk; pk.x = w0; pk.y = w1;                                    \
            *(uint2*)(plw + qn * 72 + cb * 16 + quad * 4) = pk;                \
        }                                                                      \
        const bf16x8 pfA0 = *(const bf16x8*)(plw + qn * 72 + quad * 8);        \
        const bf16x8 pfA1 = *(const bf16x8*)(plw + qn * 72 + 32 + quad * 8);   \
        __builtin_amdgcn_s_setprio(1);                                         \
        _Pragma("unroll")                                                      \
        for (int dcb = 0; dcb < 4; dcb++) {                                    \
            const bf16x8 vf0 = *(const bf16x8*)(Vs + (buf) * 4096 + quad * 512 + (dcb * 16 + qn) * 8);       \
            const bf16x8 vf1 = *(const bf16x8*)(Vs + (buf) * 4096 + (quad + 4) * 512 + (dcb * 16 + qn) * 8); \
            oA[dcb] = mfma16(pfA0, vf0, oA[dcb]);                              \
            oA[dcb] = mfma16(pfA1, vf1, oA[dcb]);                              \
        }                                                                      \
        __builtin_amdgcn_s_setprio(0);                                         \
    } while (0)

    STAGE(0, 0);
    int t = 0;
    for (; t + 2 <= ntiles; t += 2) {
        __syncthreads();
        STAGE((t + 1) * 64, 1);
        COMPUTE(t * 64, 0);
        __syncthreads();
        if (t + 2 < ntiles) STAGE((t + 2) * 64, 0);
        COMPUTE((t + 1) * 64, 1);
    }
    if (t < ntiles) {                      // odd tail: buf0 already staged
        __syncthreads();
        COMPUTE(t * 64, 0);
    }
#undef STAGE
#undef COMPUTE

    // row-sum: lanes qn, qn+16, qn+32, qn+48 hold partial sums for q-row qn
    float sA = lsum;
    sA += __shfl_xor(sA, 16, 64);
    sA += __shfl_xor(sA, 32, 64);
    #pragma unroll
    for (int i = 0; i < 4; i++) {
        const float invA = 1.0f / __shfl(sA, quad * 4 + i, 64);
        ushort_t* obA = Ob + (size_t)(trow + quad * 4 + i) * 2048 + h * 64 + qn;
        obA[0]  = f2b(oA[0][i] * invA);
        obA[16] = f2b(oA[1][i] * invA);
        obA[32] = f2b(oA[2][i] * invA);
        obA[48] = f2b(oA[3][i] * invA);
    }
}

// ---------- launch ----------
extern "C" void kernel_launch(void* const* d_in, const int* in_sizes, int n_in,
                              void* d_out, int out_size, void* d_ws, size_t ws_size,
                              hipStream_t stream) {
    const float* x    = (const float*)d_in[0];
    const float* cosp = (const float*)d_in[1];
    const float* sinp = (const float*)d_in[2];
    // d_in[3] = attention_mask_4d (pure causal; recomputed in-kernel)
    const float* Wq = (const float*)d_in[4];
    const float* Wk = (const float*)d_in[5];
    const float* Wv = (const float*)d_in[6];
    const float* Wo = (const float*)d_in[7];
    char* ws = (char*)d_ws;
    (void)ws_size; (void)in_sizes; (void)n_in; (void)out_size;

    ushort_t* xb    = (ushort_t*)(ws + WS_XB);
    ushort_t* wqkvb = (ushort_t*)(ws + WS_WQKV);
    ushort_t* wob   = (ushort_t*)(ws + WS_WO);
    ushort_t* p0    = (ushort_t*)(ws + WS_P0);
    ushort_t* p1    = (ushort_t*)(ws + WS_P1);
    ushort_t* qbb   = (ushort_t*)(ws + WS_QBB);
    ushort_t* kbb   = (ushort_t*)(ws + WS_KBB);
    ushort_t* vtg   = (ushort_t*)(ws + WS_VTG);
    ushort_t* ab    = (ushort_t*)(ws + WS_AB);

    // 1. convert inputs/weights to bf16 (contiguous dst: xb|wqkvb|wob)
    cvt_all<<<14336, 256, 0, stream>>>(x, Wq, Wk, Wv, Wo, xb);

    // 2. QKV projection split-K=2: 256^2 8-phase, 192 blocks (proven R8)
    gemm256<1><<<dim3(12, 8, 2), 512, 0, stream>>>(xb, wqkvb, p0, p1, 3072, 2048);

    // 3. fused combine + RoPE(q scale=(1/8)*log2e) + V transpose
    fuse_crv<<<dim3(48, 32), 256, 0, stream>>>(p0, p1, cosp, sinp, qbb, kbb, vtg);

    // 4. attention: 1024 blocks, 64 q-rows each (swapped-QK^T softmax)
    attn_kernel<<<1024, 256, 0, stream>>>(qbb, kbb, vtg, ab);

    // 5. O-projection: 256x64 full-K, 256 blocks = 1/CU, direct fp32 out (proven R11)
    gemm_on<<<dim3(32, 8), 512, 0, stream>>>(ab, wob, (float*)d_out, 2048, 2048);
}